// Round 2
// baseline (1048.126 us; speedup 1.0000x reference)
//
#include <hip/hip_runtime.h>
#include <hip/hip_bf16.h>

#define NB 8
#define NC 192
#define NH 48
#define NW 48
#define NP 2304        // 48*48
#define NGROUPS 32
#define CPG 6          // NC/NGROUPS
#define NEMB 192
#define NCQ 16

// ---------------- weight transpose: w[co][ci][k] -> wt[(ci*9+k)*CO + co] ----------------
__global__ __launch_bounds__(256) void transpose_w_kernel(const float* __restrict__ w,
                                                          float* __restrict__ wt,
                                                          int CO, int CI) {
  int i = blockIdx.x * 256 + threadIdx.x;
  int total = CO * CI * 9;
  if (i >= total) return;
  int co = i / (CI * 9);
  int rem = i - co * (CI * 9);
  wt[rem * CO + co] = w[i];
}

// ---------------- FeatureWiseAffine GEMV: gbsum[b][c] = 0.5*(gamma+beta) ----------------
__global__ __launch_bounds__(256) void affine_kernel(const float* __restrict__ emb,
                                                     const float* __restrict__ aw,
                                                     const float* __restrict__ ab,
                                                     float* __restrict__ gbsum) {
  int i = blockIdx.x * 256 + threadIdx.x;
  if (i >= NB * NC) return;
  int b = i / NC;
  int c = i - b * NC;
  const float* e  = emb + b * NEMB;
  const float* w0 = aw + c * NEMB;
  const float* w1 = aw + (c + NC) * NEMB;
  float s = 0.f;
  for (int j = 0; j < NEMB; ++j) s += e[j] * (w0[j] + w1[j]);
  gbsum[i] = 0.5f * (s + ab[c] + ab[c + NC]);
}

// ---------------- GroupNorm stats: per (b,g) mean + rstd ----------------
__global__ __launch_bounds__(256) void gn_stats_kernel(const float* __restrict__ in,
                                                       float* __restrict__ stats) {
  int bg = blockIdx.x;  // 0..255 = b*32+g ; group data is contiguous
  const float4* p = (const float4*)(in + (size_t)bg * (CPG * NP));
  float s = 0.f, s2 = 0.f;
  for (int i = threadIdx.x; i < CPG * NP / 4; i += 256) {
    float4 v = p[i];
    s  += v.x + v.y + v.z + v.w;
    s2 += v.x * v.x + v.y * v.y + v.z * v.z + v.w * v.w;
  }
#pragma unroll
  for (int off = 32; off > 0; off >>= 1) {
    s  += __shfl_down(s, off);
    s2 += __shfl_down(s2, off);
  }
  __shared__ float red[8];
  int wave = threadIdx.x >> 6;
  if ((threadIdx.x & 63) == 0) { red[wave * 2] = s; red[wave * 2 + 1] = s2; }
  __syncthreads();
  if (threadIdx.x == 0) {
    float S  = red[0] + red[2] + red[4] + red[6];
    float S2 = red[1] + red[3] + red[5] + red[7];
    const float invN = 1.f / (float)(CPG * NP);
    float mean = S * invN;
    float var  = S2 * invN - mean * mean;
    stats[bg * 2]     = mean;
    stats[bg * 2 + 1] = rsqrtf(var + 1e-5f);
  }
}

// ---------------- GN apply + swish ----------------
__global__ __launch_bounds__(256) void gn_apply_kernel(const float* __restrict__ in,
                                                       const float* __restrict__ stats,
                                                       const float* __restrict__ gw,
                                                       const float* __restrict__ gb,
                                                       float* __restrict__ out) {
  int i4 = blockIdx.x * 256 + threadIdx.x;
  if (i4 >= NB * NC * NP / 4) return;
  int e  = i4 * 4;
  int bc = e / NP;           // b*NC + c  (NP divisible by 4, so uniform in the float4)
  int b  = bc / NC;
  int c  = bc - b * NC;
  int g  = c / CPG;
  float mean = stats[(b * NGROUPS + g) * 2];
  float rstd = stats[(b * NGROUPS + g) * 2 + 1];
  float sc = rstd * gw[c];
  float sh = gb[c] - mean * sc;
  float4 v = *(const float4*)(in + e);
  float4 r;
  float y;
  y = v.x * sc + sh; r.x = y / (1.f + __expf(-y));
  y = v.y * sc + sh; r.y = y / (1.f + __expf(-y));
  y = v.z * sc + sh; r.z = y / (1.f + __expf(-y));
  y = v.w * sc + sh; r.w = y / (1.f + __expf(-y));
  *(float4*)(out + e) = r;
}

// ---------------- direct 3x3 conv, pad=1 ----------------
// grid: x = B*48 (b,h), y = CO/64. block 256 = 64 co-lanes x 4 w-quarters (12 w each).
// LDS reads are wave-uniform broadcasts (lanes differ only in co).
template <int CI, int CICHUNK, bool AFFINE, bool RESID>
__global__ __launch_bounds__(256) void conv3x3_kernel(const float* __restrict__ in,
                                                      const float* __restrict__ wt,
                                                      const float* __restrict__ bias,
                                                      const float* __restrict__ gbsum,
                                                      const float* resid,
                                                      float* out, int CO) {
  __shared__ float lds[CICHUNK][3][52];
  int bh = blockIdx.x;
  int b = bh / NH;
  int h = bh - b * NH;
  int co = blockIdx.y * 64 + (threadIdx.x & 63);
  int wq = threadIdx.x >> 6;
  int wb = wq * 12;
  float acc[12];
#pragma unroll
  for (int i = 0; i < 12; ++i) acc[i] = 0.f;

  for (int ci0 = 0; ci0 < CI; ci0 += CICHUNK) {
    __syncthreads();
    for (int i = threadIdx.x; i < CICHUNK * 150; i += 256) {
      int ci  = i / 150;
      int rem = i - ci * 150;
      int r   = rem / 50;
      int col = rem - r * 50;
      int hh  = h - 1 + r;
      int ww  = col - 1;
      float v = 0.f;
      if (hh >= 0 && hh < NH && (unsigned)ww < (unsigned)NW)
        v = in[((b * CI + ci0 + ci) * NH + hh) * NW + ww];
      lds[ci][r][col] = v;
    }
    __syncthreads();
    for (int ci = 0; ci < CICHUNK; ++ci) {
      float wk[9];
      const float* wp = wt + (size_t)(ci0 + ci) * 9 * CO + co;
#pragma unroll
      for (int k = 0; k < 9; ++k) wk[k] = wp[k * CO];
#pragma unroll
      for (int r = 0; r < 3; ++r) {
        float v[14];
#pragma unroll
        for (int t = 0; t < 14; ++t) v[t] = lds[ci][r][wb + t];
#pragma unroll
        for (int w = 0; w < 12; ++w)
          acc[w] += v[w] * wk[r * 3] + v[w + 1] * wk[r * 3 + 1] + v[w + 2] * wk[r * 3 + 2];
      }
    }
  }
  float bv = bias[co];
  float sfa = 0.f;
  if (AFFINE) sfa = gbsum[b * CO + co];
  int base = ((b * CO + co) * NH + h) * NW + wb;
#pragma unroll
  for (int w = 0; w < 12; ++w) {
    float v = acc[w] + bv;
    if (AFFINE) v = v * (1.f + sfa) + sfa;
    if (RESID) v += resid[base + w];
    out[base + w] = v;
  }
}

// ---------------- 1x1 conv (q: 16 out, kv: 32 out) ----------------
template <int NOUT>
__global__ __launch_bounds__(256) void conv1x1_kernel(const float* __restrict__ in,
                                                      const float* __restrict__ w,
                                                      float* __restrict__ out) {
  __shared__ float wl[NOUT * NC];
  for (int i = threadIdx.x; i < NOUT * NC; i += 256) wl[i] = w[i];
  __syncthreads();
  int b = blockIdx.y;
  int p = blockIdx.x * 256 + threadIdx.x;
  const float* ip = in + (size_t)b * NC * NP + p;
  float acc[NOUT];
#pragma unroll
  for (int o = 0; o < NOUT; ++o) acc[o] = 0.f;
  for (int ci = 0; ci < NC; ++ci) {
    float xv = ip[(size_t)ci * NP];
#pragma unroll
    for (int o = 0; o < NOUT; ++o) acc[o] += xv * wl[o * NC + ci];
  }
#pragma unroll
  for (int o = 0; o < NOUT; ++o) out[((size_t)b * NOUT + o) * NP + p] = acc[o];
}

// ---------------- flash attention: lane = query, 4 waves split keys ----------------
__global__ __launch_bounds__(256) void attn_kernel(const float* __restrict__ q,
                                                   const float* __restrict__ kv,
                                                   float* __restrict__ out) {
  __shared__ __align__(16) float kt[4][64][20];
  __shared__ __align__(16) float vt[4][64][20];
  __shared__ float part[4][64][19];
  int b    = blockIdx.y;
  int lane = threadIdx.x & 63;
  int wave = threadIdx.x >> 6;
  int p    = blockIdx.x * 64 + lane;

  float qv[16];
#pragma unroll
  for (int c = 0; c < 16; ++c) qv[c] = q[((size_t)b * 16 + c) * NP + p] * 0.25f;

  float m = -1e30f, l = 0.f;
  float acc[16];
#pragma unroll
  for (int c = 0; c < 16; ++c) acc[c] = 0.f;

  for (int t = 0; t < 9; ++t) {
    __syncthreads();
    {
      int j0 = wave * 576 + t * 64;  // each wave stages its own key-quarter tile
#pragma unroll
      for (int c = 0; c < 16; ++c) {
        kt[wave][lane][c] = kv[((size_t)b * 32 + c) * NP + j0 + lane];
        vt[wave][lane][c] = kv[((size_t)b * 32 + 16 + c) * NP + j0 + lane];
      }
    }
    __syncthreads();
    for (int j = 0; j < 64; ++j) {
      float s = 0.f;
#pragma unroll
      for (int c = 0; c < 16; ++c) s += qv[c] * kt[wave][j][c];
      if (s > m) {
        float corr = __expf(m - s);
        m = s;
        l *= corr;
#pragma unroll
        for (int c = 0; c < 16; ++c) acc[c] *= corr;
      }
      float pw = __expf(s - m);
      l += pw;
#pragma unroll
      for (int c = 0; c < 16; ++c) acc[c] += pw * vt[wave][j][c];
    }
  }
  part[wave][lane][0] = m;
  part[wave][lane][1] = l;
#pragma unroll
  for (int c = 0; c < 16; ++c) part[wave][lane][2 + c] = acc[c];
  __syncthreads();
  if (wave == 0) {
    float M = part[0][lane][0];
#pragma unroll
    for (int w = 1; w < 4; ++w) M = fmaxf(M, part[w][lane][0]);
    float L = 0.f;
    float o[16];
#pragma unroll
    for (int c = 0; c < 16; ++c) o[c] = 0.f;
#pragma unroll
    for (int w = 0; w < 4; ++w) {
      float cw = __expf(part[w][lane][0] - M);
      L += part[w][lane][1] * cw;
#pragma unroll
      for (int c = 0; c < 16; ++c) o[c] += part[w][lane][2 + c] * cw;
    }
    float inv = 1.f / L;
#pragma unroll
    for (int c = 0; c < 16; ++c) out[((size_t)b * 16 + c) * NP + p] = o[c] * inv;
  }
}

// ---------------- launch ----------------
extern "C" void kernel_launch(void* const* d_in, const int* in_sizes, int n_in,
                              void* d_out, int out_size, void* d_ws, size_t ws_size,
                              hipStream_t stream) {
  const float* x      = (const float*)d_in[0];
  const float* xe     = (const float*)d_in[1];
  const float* temb   = (const float*)d_in[2];
  const float* gn1w   = (const float*)d_in[3];
  const float* gn1b   = (const float*)d_in[4];
  const float* conv1w = (const float*)d_in[5];
  const float* conv1b = (const float*)d_in[6];
  const float* affw   = (const float*)d_in[7];
  const float* affb   = (const float*)d_in[8];
  const float* gn2w   = (const float*)d_in[9];
  const float* gn2b   = (const float*)d_in[10];
  const float* conv2w = (const float*)d_in[11];
  const float* conv2b = (const float*)d_in[12];
  const float* qw     = (const float*)d_in[13];
  const float* kvw    = (const float*)d_in[14];
  const float* outw   = (const float*)d_in[15];
  const float* outb   = (const float*)d_in[16];
  float* out = (float*)d_out;
  float* ws  = (float*)d_ws;

  const size_t TENS = (size_t)NB * NC * NP;  // 3,538,944
  float* bufA  = ws;                  // act1 / act2
  float* qbuf  = bufA + TENS;         // 294,912
  float* kvbuf = qbuf + (size_t)NB * 16 * NP;   // 589,824
  float* aobuf = kvbuf + (size_t)NB * 32 * NP;  // 294,912
  float* gbsum = aobuf + (size_t)NB * 16 * NP;  // 1536
  float* stats = gbsum + NB * NC;               // 512
  float* wt1   = stats + 512;                   // 331,776
  float* wt2   = wt1 + (size_t)NC * NC * 9;
  float* wto   = wt2 + (size_t)NC * NC * 9;     // 27,648

  // weight transposes (tiny)
  transpose_w_kernel<<<(NC * NC * 9 + 255) / 256, 256, 0, stream>>>(conv1w, wt1, NC, NC);
  transpose_w_kernel<<<(NC * NC * 9 + 255) / 256, 256, 0, stream>>>(conv2w, wt2, NC, NC);
  transpose_w_kernel<<<(NC * NCQ * 9 + 255) / 256, 256, 0, stream>>>(outw, wto, NC, NCQ);
  // affine gemv
  affine_kernel<<<6, 256, 0, stream>>>(temb, affw, affb, gbsum);

  // ----- ResnetBlock -----
  gn_stats_kernel<<<NB * NGROUPS, 256, 0, stream>>>(x, stats);
  gn_apply_kernel<<<(int)(TENS / 4 / 256), 256, 0, stream>>>(x, stats, gn1w, gn1b, bufA);
  // conv1 + bias + affine -> h (stored in d_out)
  conv3x3_kernel<NC, 32, true, false><<<dim3(NB * NH, 3), 256, 0, stream>>>(
      bufA, wt1, conv1b, gbsum, nullptr, out, NC);
  gn_stats_kernel<<<NB * NGROUPS, 256, 0, stream>>>(out, stats);
  gn_apply_kernel<<<(int)(TENS / 4 / 256), 256, 0, stream>>>(out, stats, gn2w, gn2b, bufA);
  // conv2 + bias + x -> xres (stored in d_out)
  conv3x3_kernel<NC, 32, false, true><<<dim3(NB * NH, 3), 256, 0, stream>>>(
      bufA, wt2, conv2b, nullptr, x, out, NC);

  // ----- CrossAttention -----
  conv1x1_kernel<16><<<dim3(9, NB), 256, 0, stream>>>(out, qw, qbuf);
  conv1x1_kernel<32><<<dim3(9, NB), 256, 0, stream>>>(xe, kvw, kvbuf);
  attn_kernel<<<dim3(36, NB), 256, 0, stream>>>(qbuf, kvbuf, aobuf);
  // out conv + bias + xres (in-place per-element on d_out)
  conv3x3_kernel<NCQ, 16, false, true><<<dim3(NB * NH, 3), 256, 0, stream>>>(
      aobuf, wto, outb, nullptr, out, out, NC);
}

// Round 3
// 538.368 us; speedup vs baseline: 1.9469x; 1.9469x over previous
//
#include <hip/hip_runtime.h>
#include <hip/hip_bf16.h>

#define NB 8
#define NC 192
#define NH 48
#define NW 48
#define NP 2304        // 48*48
#define NGROUPS 32
#define CPG 6          // NC/NGROUPS
#define NEMB 192
#define NCQ 16

// padded-transposed activation: [B][50 h'][52 w' stride (50 used)][192 c] bf16
#define PH 50
#define PWS 52
#define ACT_T_ELEMS ((size_t)NB * PH * PWS * NC)   // 3,993,600 bf16

typedef __attribute__((ext_vector_type(4))) short s16x4;
typedef __attribute__((ext_vector_type(8))) short s16x8;
typedef __attribute__((ext_vector_type(4))) float f32x4;

static __device__ inline short f2bf(float v) {
  __hip_bfloat16 h = __float2bfloat16(v);
  return *(short*)&h;
}

// ---------------- weight transpose (out conv only): w[co][ci][k] -> wt[(ci*9+k)*CO+co]
__global__ __launch_bounds__(256) void transpose_w_kernel(const float* __restrict__ w,
                                                          float* __restrict__ wt,
                                                          int CO, int CI) {
  int i = blockIdx.x * 256 + threadIdx.x;
  int total = CO * CI * 9;
  if (i >= total) return;
  int co = i / (CI * 9);
  int rem = i - co * (CI * 9);
  wt[rem * CO + co] = w[i];
}

// ---------------- MFMA weight prep: wbuf[kc(6)][t(9)][cf(12)][lane(64)][j(8)] bf16
// co = cf*16 + (lane&15), ci = kc*32 + (lane>>4)*8 + j, tap t = ky*3+kx
__global__ __launch_bounds__(256) void wprep_kernel(const float* __restrict__ w,
                                                    short* __restrict__ wbuf) {
  int i = blockIdx.x * 256 + threadIdx.x;
  if (i >= 6 * 9 * 12 * 64 * 8) return;
  int j  = i & 7;
  int l  = (i >> 3) & 63;
  int cf = (i >> 9) % 12;
  int tk = (i >> 9) / 12;      // kc*9 + t
  int t  = tk % 9;
  int kc = tk / 9;
  int co = cf * 16 + (l & 15);
  int ci = kc * 32 + (l >> 4) * 8 + j;
  wbuf[i] = f2bf(w[((size_t)co * NC + ci) * 9 + t]);
}

// ---------------- FeatureWiseAffine GEMV: gbsum[b][c] = 0.5*(gamma+beta) ----------------
__global__ __launch_bounds__(256) void affine_kernel(const float* __restrict__ emb,
                                                     const float* __restrict__ aw,
                                                     const float* __restrict__ ab,
                                                     float* __restrict__ gbsum) {
  int i = blockIdx.x * 256 + threadIdx.x;
  if (i >= NB * NC) return;
  int b = i / NC;
  int c = i - b * NC;
  const float* e  = emb + b * NEMB;
  const float* w0 = aw + c * NEMB;
  const float* w1 = aw + (c + NC) * NEMB;
  float s = 0.f;
  for (int j = 0; j < NEMB; ++j) s += e[j] * (w0[j] + w1[j]);
  gbsum[i] = 0.5f * (s + ab[c] + ab[c + NC]);
}

// ---------------- GroupNorm stats: per (b,g) mean + rstd ----------------
__global__ __launch_bounds__(256) void gn_stats_kernel(const float* __restrict__ in,
                                                       float* __restrict__ stats) {
  int bg = blockIdx.x;  // b*32+g ; group data contiguous
  const float4* p = (const float4*)(in + (size_t)bg * (CPG * NP));
  float s = 0.f, s2 = 0.f;
  for (int i = threadIdx.x; i < CPG * NP / 4; i += 256) {
    float4 v = p[i];
    s  += v.x + v.y + v.z + v.w;
    s2 += v.x * v.x + v.y * v.y + v.z * v.z + v.w * v.w;
  }
#pragma unroll
  for (int off = 32; off > 0; off >>= 1) {
    s  += __shfl_down(s, off);
    s2 += __shfl_down(s2, off);
  }
  __shared__ float red[8];
  int wave = threadIdx.x >> 6;
  if ((threadIdx.x & 63) == 0) { red[wave * 2] = s; red[wave * 2 + 1] = s2; }
  __syncthreads();
  if (threadIdx.x == 0) {
    float S  = red[0] + red[2] + red[4] + red[6];
    float S2 = red[1] + red[3] + red[5] + red[7];
    const float invN = 1.f / (float)(CPG * NP);
    float mean = S * invN;
    float var  = S2 * invN - mean * mean;
    stats[bg * 2]     = mean;
    stats[bg * 2 + 1] = rsqrtf(var + 1e-5f);
  }
}

// ---------------- GN apply + swish -> padded TRANSPOSED bf16 act_t[b][h+1][w+1][c] ----
// one block per (b,h); LDS transpose so both global read and write are coalesced.
__global__ __launch_bounds__(256) void gn_apply_t_kernel(const float* __restrict__ in,
                                                         const float* __restrict__ stats,
                                                         const float* __restrict__ gw,
                                                         const float* __restrict__ gb,
                                                         short* __restrict__ actt) {
  __shared__ float tile[48 * 193];  // [w][c], stride 193 breaks bank alignment
  int bh = blockIdx.x;
  int b = bh / NH;
  int h = bh - b * NH;
  int tid = threadIdx.x;
  // phase 1: read [c][w] coalesced (float4 along w), GN+swish, store transposed
  for (int i = tid; i < 2304; i += 256) {
    int c = i / 12;
    int w = (i % 12) * 4;
    float4 v = *(const float4*)(in + (((size_t)b * NC + c) * NH + h) * NW + w);
    float mean = stats[(b * NGROUPS + c / CPG) * 2];
    float rstd = stats[(b * NGROUPS + c / CPG) * 2 + 1];
    float sc = rstd * gw[c];
    float sh = gb[c] - mean * sc;
    float y;
    y = v.x * sc + sh; tile[(w + 0) * 193 + c] = y / (1.f + __expf(-y));
    y = v.y * sc + sh; tile[(w + 1) * 193 + c] = y / (1.f + __expf(-y));
    y = v.z * sc + sh; tile[(w + 2) * 193 + c] = y / (1.f + __expf(-y));
    y = v.w * sc + sh; tile[(w + 3) * 193 + c] = y / (1.f + __expf(-y));
  }
  __syncthreads();
  // phase 2: read [w][c], write bf16 [h'][w'][c] coalesced (short4 along c)
  short* dst = actt + (((size_t)b * PH + h + 1) * PWS + 1) * NC;
  for (int i = tid; i < 2304; i += 256) {
    int w  = i / 48;
    int c4 = (i - w * 48) * 4;
    s16x4 o;
    o.x = f2bf(tile[w * 193 + c4 + 0]);
    o.y = f2bf(tile[w * 193 + c4 + 1]);
    o.z = f2bf(tile[w * 193 + c4 + 2]);
    o.w = f2bf(tile[w * 193 + c4 + 3]);
    *(s16x4*)(dst + (size_t)w * NC + c4) = o;
  }
}

// ---------------- conv3x3 via MFMA (tap-decomposed implicit GEMM) ----------------
// grid: x = b*24 + strip (2 rows each), y = co-block (3 x 64co). 4 waves.
// wave (wy,wx): 32 co x 48 px (one row). B staged [4 rows][50 cols][40-pad 32ci] bf16.
// A-frags direct from L2 (wbuf, MFMA-ready). D: col=lane&15 (px), row=(lane>>4)*4+r (co).
template <bool AFFINE, bool RESID>
__global__ __launch_bounds__(256) void conv_mfma_kernel(const short* __restrict__ actt,
                                                        const short* __restrict__ wbuf,
                                                        const float* __restrict__ bias,
                                                        const float* __restrict__ gbsum,
                                                        const float* __restrict__ resid,
                                                        float* __restrict__ out) {
  __shared__ short S[4][50][40];   // 16 KB; col stride 80B -> ~2-way banks on b128 reads
  int bs = blockIdx.x;
  int b = bs / 24;
  int strip = bs - b * 24;
  int coB = blockIdx.y;
  int h0 = strip * 2;
  int tid = threadIdx.x;
  int lane = tid & 63, wave = tid >> 6;
  int wy = wave >> 1, wx = wave & 1;
  int g8 = (lane >> 4) * 8;

  f32x4 acc[2][3];
#pragma unroll
  for (int m = 0; m < 2; ++m)
#pragma unroll
    for (int f = 0; f < 3; ++f) acc[m][f] = (f32x4){0.f, 0.f, 0.f, 0.f};

  const size_t actbase = ((size_t)b * PH + h0) * PWS * NC;  // h' = h0 + r covers h0-1..h0+2

  for (int kc = 0; kc < 6; ++kc) {
    __syncthreads();
    // stage 4x50x32 bf16 (b128 granules: 800 16B-loads)
    for (int i = tid; i < 800; i += 256) {
      int ci8 = i & 3;
      int rc  = i >> 2;          // 0..199
      int col = rc % 50, r = rc / 50;
      const s16x8* src = (const s16x8*)(actt + actbase + ((size_t)r * PWS + col) * NC +
                                        kc * 32 + ci8 * 8);
      *(s16x8*)(&S[r][col][ci8 * 8]) = *src;
    }
    __syncthreads();
#pragma unroll
    for (int t = 0; t < 9; ++t) {
      int ky = t / 3, kx = t - ky * 3;
      const short* wp = wbuf + ((((size_t)kc * 9 + t) * 12 + (coB * 4 + wy * 2)) * 64 + lane) * 8;
      s16x8 a0 = *(const s16x8*)wp;
      s16x8 a1 = *(const s16x8*)(wp + 64 * 8);
      int row = wx + ky;
#pragma unroll
      for (int f = 0; f < 3; ++f) {
        int col = f * 16 + (lane & 15) + kx;
        s16x8 bf = *(const s16x8*)(&S[row][col][g8]);
        acc[0][f] = __builtin_amdgcn_mfma_f32_16x16x32_bf16(a0, bf, acc[0][f], 0, 0, 0);
        acc[1][f] = __builtin_amdgcn_mfma_f32_16x16x32_bf16(a1, bf, acc[1][f], 0, 0, 0);
      }
    }
  }
  // epilogue
  int hout = h0 + wx;
#pragma unroll
  for (int m = 0; m < 2; ++m) {
    int co0 = coB * 64 + wy * 32 + m * 16;
#pragma unroll
    for (int r = 0; r < 4; ++r) {
      int co = co0 + (lane >> 4) * 4 + r;
      float bv = bias[co];
      float s = AFFINE ? gbsum[b * NC + co] : 0.f;
#pragma unroll
      for (int f = 0; f < 3; ++f) {
        int w = f * 16 + (lane & 15);
        size_t o = (((size_t)b * NC + co) * NH + hout) * NW + w;
        float v = acc[m][f][r] + bv;
        if (AFFINE) v = v * (1.f + s) + s;
        if (RESID) v += resid[o];
        out[o] = v;
      }
    }
  }
}

// ---------------- direct 3x3 conv (small CI; used for out conv) ----------------
template <int CI, int CICHUNK, bool AFFINE, bool RESID>
__global__ __launch_bounds__(256) void conv3x3_kernel(const float* __restrict__ in,
                                                      const float* __restrict__ wt,
                                                      const float* __restrict__ bias,
                                                      const float* __restrict__ gbsum,
                                                      const float* resid,
                                                      float* out, int CO) {
  __shared__ float lds[CICHUNK][3][52];
  int bh = blockIdx.x;
  int b = bh / NH;
  int h = bh - b * NH;
  int co = blockIdx.y * 64 + (threadIdx.x & 63);
  int wq = threadIdx.x >> 6;
  int wb = wq * 12;
  float acc[12];
#pragma unroll
  for (int i = 0; i < 12; ++i) acc[i] = 0.f;

  for (int ci0 = 0; ci0 < CI; ci0 += CICHUNK) {
    __syncthreads();
    for (int i = threadIdx.x; i < CICHUNK * 150; i += 256) {
      int ci  = i / 150;
      int rem = i - ci * 150;
      int r   = rem / 50;
      int col = rem - r * 50;
      int hh  = h - 1 + r;
      int ww  = col - 1;
      float v = 0.f;
      if (hh >= 0 && hh < NH && (unsigned)ww < (unsigned)NW)
        v = in[((b * CI + ci0 + ci) * NH + hh) * NW + ww];
      lds[ci][r][col] = v;
    }
    __syncthreads();
    for (int ci = 0; ci < CICHUNK; ++ci) {
      float wk[9];
      const float* wp = wt + (size_t)(ci0 + ci) * 9 * CO + co;
#pragma unroll
      for (int k = 0; k < 9; ++k) wk[k] = wp[k * CO];
#pragma unroll
      for (int r = 0; r < 3; ++r) {
        float v[14];
#pragma unroll
        for (int t = 0; t < 14; ++t) v[t] = lds[ci][r][wb + t];
#pragma unroll
        for (int w = 0; w < 12; ++w)
          acc[w] += v[w] * wk[r * 3] + v[w + 1] * wk[r * 3 + 1] + v[w + 2] * wk[r * 3 + 2];
      }
    }
  }
  float bv = bias[co];
  float sfa = 0.f;
  if (AFFINE) sfa = gbsum[b * CO + co];
  int base = ((b * CO + co) * NH + h) * NW + wb;
#pragma unroll
  for (int w = 0; w < 12; ++w) {
    float v = acc[w] + bv;
    if (AFFINE) v = v * (1.f + sfa) + sfa;
    if (RESID) v += resid[base + w];
    out[base + w] = v;
  }
}

// ---------------- 1x1 conv (q: 16 out, kv: 32 out) ----------------
template <int NOUT>
__global__ __launch_bounds__(256) void conv1x1_kernel(const float* __restrict__ in,
                                                      const float* __restrict__ w,
                                                      float* __restrict__ out) {
  __shared__ float wl[NOUT * NC];
  for (int i = threadIdx.x; i < NOUT * NC; i += 256) wl[i] = w[i];
  __syncthreads();
  int b = blockIdx.y;
  int p = blockIdx.x * 256 + threadIdx.x;
  const float* ip = in + (size_t)b * NC * NP + p;
  float acc[NOUT];
#pragma unroll
  for (int o = 0; o < NOUT; ++o) acc[o] = 0.f;
  for (int ci = 0; ci < NC; ++ci) {
    float xv = ip[(size_t)ci * NP];
#pragma unroll
    for (int o = 0; o < NOUT; ++o) acc[o] += xv * wl[o * NC + ci];
  }
#pragma unroll
  for (int o = 0; o < NOUT; ++o) out[((size_t)b * NOUT + o) * NP + p] = acc[o];
}

// ---------------- flash attention: lane = query, 4 waves split keys ----------------
__global__ __launch_bounds__(256) void attn_kernel(const float* __restrict__ q,
                                                   const float* __restrict__ kv,
                                                   float* __restrict__ out) {
  __shared__ __align__(16) float kt[4][64][20];
  __shared__ __align__(16) float vt[4][64][20];
  __shared__ float part[4][64][19];
  int b    = blockIdx.y;
  int lane = threadIdx.x & 63;
  int wave = threadIdx.x >> 6;
  int p    = blockIdx.x * 64 + lane;

  float qv[16];
#pragma unroll
  for (int c = 0; c < 16; ++c) qv[c] = q[((size_t)b * 16 + c) * NP + p] * 0.25f;

  float m = -1e30f, l = 0.f;
  float acc[16];
#pragma unroll
  for (int c = 0; c < 16; ++c) acc[c] = 0.f;

  for (int t = 0; t < 9; ++t) {
    __syncthreads();
    {
      int j0 = wave * 576 + t * 64;
#pragma unroll
      for (int c = 0; c < 16; ++c) {
        kt[wave][lane][c] = kv[((size_t)b * 32 + c) * NP + j0 + lane];
        vt[wave][lane][c] = kv[((size_t)b * 32 + 16 + c) * NP + j0 + lane];
      }
    }
    __syncthreads();
    for (int j = 0; j < 64; ++j) {
      float s = 0.f;
#pragma unroll
      for (int c = 0; c < 16; ++c) s += qv[c] * kt[wave][j][c];
      if (s > m) {
        float corr = __expf(m - s);
        m = s;
        l *= corr;
#pragma unroll
        for (int c = 0; c < 16; ++c) acc[c] *= corr;
      }
      float pw = __expf(s - m);
      l += pw;
#pragma unroll
      for (int c = 0; c < 16; ++c) acc[c] += pw * vt[wave][j][c];
    }
  }
  part[wave][lane][0] = m;
  part[wave][lane][1] = l;
#pragma unroll
  for (int c = 0; c < 16; ++c) part[wave][lane][2 + c] = acc[c];
  __syncthreads();
  if (wave == 0) {
    float M = part[0][lane][0];
#pragma unroll
    for (int w = 1; w < 4; ++w) M = fmaxf(M, part[w][lane][0]);
    float L = 0.f;
    float o[16];
#pragma unroll
    for (int c = 0; c < 16; ++c) o[c] = 0.f;
#pragma unroll
    for (int w = 0; w < 4; ++w) {
      float cw = __expf(part[w][lane][0] - M);
      L += part[w][lane][1] * cw;
#pragma unroll
      for (int c = 0; c < 16; ++c) o[c] += part[w][lane][2 + c] * cw;
    }
    float inv = 1.f / L;
#pragma unroll
    for (int c = 0; c < 16; ++c) out[((size_t)b * 16 + c) * NP + p] = o[c] * inv;
  }
}

// ---------------- launch ----------------
extern "C" void kernel_launch(void* const* d_in, const int* in_sizes, int n_in,
                              void* d_out, int out_size, void* d_ws, size_t ws_size,
                              hipStream_t stream) {
  const float* x      = (const float*)d_in[0];
  const float* xe     = (const float*)d_in[1];
  const float* temb   = (const float*)d_in[2];
  const float* gn1w   = (const float*)d_in[3];
  const float* gn1b   = (const float*)d_in[4];
  const float* conv1w = (const float*)d_in[5];
  const float* conv1b = (const float*)d_in[6];
  const float* affw   = (const float*)d_in[7];
  const float* affb   = (const float*)d_in[8];
  const float* gn2w   = (const float*)d_in[9];
  const float* gn2b   = (const float*)d_in[10];
  const float* conv2w = (const float*)d_in[11];
  const float* conv2b = (const float*)d_in[12];
  const float* qw     = (const float*)d_in[13];
  const float* kvw    = (const float*)d_in[14];
  const float* outw   = (const float*)d_in[15];
  const float* outb   = (const float*)d_in[16];
  float* out = (float*)d_out;
  float* ws  = (float*)d_ws;

  // ws layout (float slots, all 16B-aligned)
  float* qbuf  = ws;                                  // 294,912
  float* kvbuf = qbuf + (size_t)NB * 16 * NP;         // 589,824
  float* aobuf = kvbuf + (size_t)NB * 32 * NP;        // 294,912
  float* gbsum = aobuf + (size_t)NB * 16 * NP;        // 1,536
  float* stats = gbsum + NB * NC;                     // 512
  float* wto   = stats + 512;                         // 27,648
  short* wbuf1 = (short*)(wto + (size_t)NC * NCQ * 9);        // 331,776 bf16
  short* wbuf2 = wbuf1 + (size_t)6 * 9 * 12 * 64 * 8;         // 331,776 bf16
  short* actt  = wbuf2 + (size_t)6 * 9 * 12 * 64 * 8;         // 3,993,600 bf16

  // prep (weights, affine)
  wprep_kernel<<<1296, 256, 0, stream>>>(conv1w, wbuf1);
  wprep_kernel<<<1296, 256, 0, stream>>>(conv2w, wbuf2);
  transpose_w_kernel<<<108, 256, 0, stream>>>(outw, wto, NC, NCQ);
  affine_kernel<<<6, 256, 0, stream>>>(temb, affw, affb, gbsum);
  // zero padded act_t once; both GN passes only rewrite the interior
  hipMemsetAsync(actt, 0, ACT_T_ELEMS * sizeof(short), stream);

  // ----- ResnetBlock -----
  gn_stats_kernel<<<NB * NGROUPS, 256, 0, stream>>>(x, stats);
  gn_apply_t_kernel<<<NB * NH, 256, 0, stream>>>(x, stats, gn1w, gn1b, actt);
  conv_mfma_kernel<true, false><<<dim3(NB * 24, 3), 256, 0, stream>>>(
      actt, wbuf1, conv1b, gbsum, nullptr, out);              // h -> d_out
  gn_stats_kernel<<<NB * NGROUPS, 256, 0, stream>>>(out, stats);
  gn_apply_t_kernel<<<NB * NH, 256, 0, stream>>>(out, stats, gn2w, gn2b, actt);
  conv_mfma_kernel<false, true><<<dim3(NB * 24, 3), 256, 0, stream>>>(
      actt, wbuf2, conv2b, nullptr, x, out);                  // xres -> d_out

  // ----- CrossAttention -----
  conv1x1_kernel<16><<<dim3(9, NB), 256, 0, stream>>>(out, qw, qbuf);
  conv1x1_kernel<32><<<dim3(9, NB), 256, 0, stream>>>(xe, kvw, kvbuf);
  attn_kernel<<<dim3(36, NB), 256, 0, stream>>>(qbuf, kvbuf, aobuf);
  conv3x3_kernel<NCQ, 16, false, true><<<dim3(NB * NH, 3), 256, 0, stream>>>(
      aobuf, wto, outb, nullptr, out, out, NC);
}

// Round 4
// 388.765 us; speedup vs baseline: 2.6960x; 1.3848x over previous
//
#include <hip/hip_runtime.h>
#include <hip/hip_bf16.h>

#define NB 8
#define NC 192
#define NH 48
#define NW 48
#define NP 2304        // 48*48
#define NGROUPS 32
#define CPG 6          // NC/NGROUPS
#define NEMB 192
#define NCQ 16

// padded-transposed activation: [B][50 h'][52 w' stride (50 used)][192 c] bf16
#define PH 50
#define PWS 52
#define ACT_T_ELEMS ((size_t)NB * PH * PWS * NC)   // 3,993,600 bf16

typedef __attribute__((ext_vector_type(4))) short s16x4;
typedef __attribute__((ext_vector_type(8))) short s16x8;
typedef __attribute__((ext_vector_type(4))) float f32x4;

static __device__ inline short f2bf(float v) {
  __hip_bfloat16 h = __float2bfloat16(v);
  return *(short*)&h;
}

// ---------------- weight transpose (out conv only): w[co][ci][k] -> wt[(ci*9+k)*CO+co]
__global__ __launch_bounds__(256) void transpose_w_kernel(const float* __restrict__ w,
                                                          float* __restrict__ wt,
                                                          int CO, int CI) {
  int i = blockIdx.x * 256 + threadIdx.x;
  int total = CO * CI * 9;
  if (i >= total) return;
  int co = i / (CI * 9);
  int rem = i - co * (CI * 9);
  wt[rem * CO + co] = w[i];
}

// ---------------- MFMA weight prep: wbuf[kc(6)][t(9)][cf(12)][lane(64)][j(8)] bf16
__global__ __launch_bounds__(256) void wprep_kernel(const float* __restrict__ w,
                                                    short* __restrict__ wbuf) {
  int i = blockIdx.x * 256 + threadIdx.x;
  if (i >= 6 * 9 * 12 * 64 * 8) return;
  int j  = i & 7;
  int l  = (i >> 3) & 63;
  int cf = (i >> 9) % 12;
  int tk = (i >> 9) / 12;      // kc*9 + t
  int t  = tk % 9;
  int kc = tk / 9;
  int co = cf * 16 + (l & 15);
  int ci = kc * 32 + (l >> 4) * 8 + j;
  wbuf[i] = f2bf(w[((size_t)co * NC + ci) * 9 + t]);
}

// ---------------- FeatureWiseAffine GEMV ----------------
__global__ __launch_bounds__(256) void affine_kernel(const float* __restrict__ emb,
                                                     const float* __restrict__ aw,
                                                     const float* __restrict__ ab,
                                                     float* __restrict__ gbsum) {
  int i = blockIdx.x * 256 + threadIdx.x;
  if (i >= NB * NC) return;
  int b = i / NC;
  int c = i - b * NC;
  const float* e  = emb + b * NEMB;
  const float* w0 = aw + c * NEMB;
  const float* w1 = aw + (c + NC) * NEMB;
  float s = 0.f;
  for (int j = 0; j < NEMB; ++j) s += e[j] * (w0[j] + w1[j]);
  gbsum[i] = 0.5f * (s + ab[c] + ab[c + NC]);
}

// ---------------- GroupNorm stats ----------------
__global__ __launch_bounds__(256) void gn_stats_kernel(const float* __restrict__ in,
                                                       float* __restrict__ stats) {
  int bg = blockIdx.x;
  const float4* p = (const float4*)(in + (size_t)bg * (CPG * NP));
  float s = 0.f, s2 = 0.f;
  for (int i = threadIdx.x; i < CPG * NP / 4; i += 256) {
    float4 v = p[i];
    s  += v.x + v.y + v.z + v.w;
    s2 += v.x * v.x + v.y * v.y + v.z * v.z + v.w * v.w;
  }
#pragma unroll
  for (int off = 32; off > 0; off >>= 1) {
    s  += __shfl_down(s, off);
    s2 += __shfl_down(s2, off);
  }
  __shared__ float red[8];
  int wave = threadIdx.x >> 6;
  if ((threadIdx.x & 63) == 0) { red[wave * 2] = s; red[wave * 2 + 1] = s2; }
  __syncthreads();
  if (threadIdx.x == 0) {
    float S  = red[0] + red[2] + red[4] + red[6];
    float S2 = red[1] + red[3] + red[5] + red[7];
    const float invN = 1.f / (float)(CPG * NP);
    float mean = S * invN;
    float var  = S2 * invN - mean * mean;
    stats[bg * 2]     = mean;
    stats[bg * 2 + 1] = rsqrtf(var + 1e-5f);
  }
}

// ---------------- GN apply + swish -> padded TRANSPOSED bf16 act_t ----------------
__global__ __launch_bounds__(256) void gn_apply_t_kernel(const float* __restrict__ in,
                                                         const float* __restrict__ stats,
                                                         const float* __restrict__ gw,
                                                         const float* __restrict__ gb,
                                                         short* __restrict__ actt) {
  __shared__ float tile[48 * 193];
  int bh = blockIdx.x;
  int b = bh / NH;
  int h = bh - b * NH;
  int tid = threadIdx.x;
  for (int i = tid; i < 2304; i += 256) {
    int c = i / 12;
    int w = (i % 12) * 4;
    float4 v = *(const float4*)(in + (((size_t)b * NC + c) * NH + h) * NW + w);
    float mean = stats[(b * NGROUPS + c / CPG) * 2];
    float rstd = stats[(b * NGROUPS + c / CPG) * 2 + 1];
    float sc = rstd * gw[c];
    float sh = gb[c] - mean * sc;
    float y;
    y = v.x * sc + sh; tile[(w + 0) * 193 + c] = y / (1.f + __expf(-y));
    y = v.y * sc + sh; tile[(w + 1) * 193 + c] = y / (1.f + __expf(-y));
    y = v.z * sc + sh; tile[(w + 2) * 193 + c] = y / (1.f + __expf(-y));
    y = v.w * sc + sh; tile[(w + 3) * 193 + c] = y / (1.f + __expf(-y));
  }
  __syncthreads();
  short* dst = actt + (((size_t)b * PH + h + 1) * PWS + 1) * NC;
  for (int i = tid; i < 2304; i += 256) {
    int w  = i / 48;
    int c4 = (i - w * 48) * 4;
    s16x4 o;
    o.x = f2bf(tile[w * 193 + c4 + 0]);
    o.y = f2bf(tile[w * 193 + c4 + 1]);
    o.z = f2bf(tile[w * 193 + c4 + 2]);
    o.w = f2bf(tile[w * 193 + c4 + 3]);
    *(s16x4*)(dst + (size_t)w * NC + c4) = o;
  }
}

// ---------------- conv3x3 via MFMA (tap-decomposed implicit GEMM) ----------------
template <bool AFFINE, bool RESID>
__global__ __launch_bounds__(256) void conv_mfma_kernel(const short* __restrict__ actt,
                                                        const short* __restrict__ wbuf,
                                                        const float* __restrict__ bias,
                                                        const float* __restrict__ gbsum,
                                                        const float* __restrict__ resid,
                                                        float* __restrict__ out) {
  __shared__ short S[4][50][40];
  int bs = blockIdx.x;
  int b = bs / 24;
  int strip = bs - b * 24;
  int coB = blockIdx.y;
  int h0 = strip * 2;
  int tid = threadIdx.x;
  int lane = tid & 63, wave = tid >> 6;
  int wy = wave >> 1, wx = wave & 1;
  int g8 = (lane >> 4) * 8;

  f32x4 acc[2][3];
#pragma unroll
  for (int m = 0; m < 2; ++m)
#pragma unroll
    for (int f = 0; f < 3; ++f) acc[m][f] = (f32x4){0.f, 0.f, 0.f, 0.f};

  const size_t actbase = ((size_t)b * PH + h0) * PWS * NC;

  for (int kc = 0; kc < 6; ++kc) {
    __syncthreads();
    for (int i = tid; i < 800; i += 256) {
      int ci8 = i & 3;
      int rc  = i >> 2;
      int col = rc % 50, r = rc / 50;
      const s16x8* src = (const s16x8*)(actt + actbase + ((size_t)r * PWS + col) * NC +
                                        kc * 32 + ci8 * 8);
      *(s16x8*)(&S[r][col][ci8 * 8]) = *src;
    }
    __syncthreads();
#pragma unroll
    for (int t = 0; t < 9; ++t) {
      int ky = t / 3, kx = t - ky * 3;
      const short* wp = wbuf + ((((size_t)kc * 9 + t) * 12 + (coB * 4 + wy * 2)) * 64 + lane) * 8;
      s16x8 a0 = *(const s16x8*)wp;
      s16x8 a1 = *(const s16x8*)(wp + 64 * 8);
      int row = wx + ky;
#pragma unroll
      for (int f = 0; f < 3; ++f) {
        int col = f * 16 + (lane & 15) + kx;
        s16x8 bf = *(const s16x8*)(&S[row][col][g8]);
        acc[0][f] = __builtin_amdgcn_mfma_f32_16x16x32_bf16(a0, bf, acc[0][f], 0, 0, 0);
        acc[1][f] = __builtin_amdgcn_mfma_f32_16x16x32_bf16(a1, bf, acc[1][f], 0, 0, 0);
      }
    }
  }
  int hout = h0 + wx;
#pragma unroll
  for (int m = 0; m < 2; ++m) {
    int co0 = coB * 64 + wy * 32 + m * 16;
#pragma unroll
    for (int r = 0; r < 4; ++r) {
      int co = co0 + (lane >> 4) * 4 + r;
      float bv = bias[co];
      float s = AFFINE ? gbsum[b * NC + co] : 0.f;
#pragma unroll
      for (int f = 0; f < 3; ++f) {
        int w = f * 16 + (lane & 15);
        size_t o = (((size_t)b * NC + co) * NH + hout) * NW + w;
        float v = acc[m][f][r] + bv;
        if (AFFINE) v = v * (1.f + s) + s;
        if (RESID) v += resid[o];
        out[o] = v;
      }
    }
  }
}

// ---------------- direct 3x3 conv (small CI; used for out conv) ----------------
template <int CI, int CICHUNK, bool AFFINE, bool RESID>
__global__ __launch_bounds__(256) void conv3x3_kernel(const float* __restrict__ in,
                                                      const float* __restrict__ wt,
                                                      const float* __restrict__ bias,
                                                      const float* __restrict__ gbsum,
                                                      const float* resid,
                                                      float* out, int CO) {
  __shared__ float lds[CICHUNK][3][52];
  int bh = blockIdx.x;
  int b = bh / NH;
  int h = bh - b * NH;
  int co = blockIdx.y * 64 + (threadIdx.x & 63);
  int wq = threadIdx.x >> 6;
  int wb = wq * 12;
  float acc[12];
#pragma unroll
  for (int i = 0; i < 12; ++i) acc[i] = 0.f;

  for (int ci0 = 0; ci0 < CI; ci0 += CICHUNK) {
    __syncthreads();
    for (int i = threadIdx.x; i < CICHUNK * 150; i += 256) {
      int ci  = i / 150;
      int rem = i - ci * 150;
      int r   = rem / 50;
      int col = rem - r * 50;
      int hh  = h - 1 + r;
      int ww  = col - 1;
      float v = 0.f;
      if (hh >= 0 && hh < NH && (unsigned)ww < (unsigned)NW)
        v = in[((b * CI + ci0 + ci) * NH + hh) * NW + ww];
      lds[ci][r][col] = v;
    }
    __syncthreads();
    for (int ci = 0; ci < CICHUNK; ++ci) {
      float wk[9];
      const float* wp = wt + (size_t)(ci0 + ci) * 9 * CO + co;
#pragma unroll
      for (int k = 0; k < 9; ++k) wk[k] = wp[k * CO];
#pragma unroll
      for (int r = 0; r < 3; ++r) {
        float v[14];
#pragma unroll
        for (int t = 0; t < 14; ++t) v[t] = lds[ci][r][wb + t];
#pragma unroll
        for (int w = 0; w < 12; ++w)
          acc[w] += v[w] * wk[r * 3] + v[w + 1] * wk[r * 3 + 1] + v[w + 2] * wk[r * 3 + 2];
      }
    }
  }
  float bv = bias[co];
  float sfa = 0.f;
  if (AFFINE) sfa = gbsum[b * CO + co];
  int base = ((b * CO + co) * NH + h) * NW + wb;
#pragma unroll
  for (int w = 0; w < 12; ++w) {
    float v = acc[w] + bv;
    if (AFFINE) v = v * (1.f + sfa) + sfa;
    if (RESID) v += resid[base + w];
    out[base + w] = v;
  }
}

// ---------------- q prep: 1x1 conv -> Q[b][p][32] bf16, scale*log2e folded, d16-31 = 0
__global__ __launch_bounds__(256) void qprep_kernel(const float* __restrict__ in,
                                                    const float* __restrict__ w,
                                                    short* __restrict__ Qb) {
  __shared__ float wl[16 * NC];
  for (int i = threadIdx.x; i < 16 * NC; i += 256) wl[i] = w[i];
  __syncthreads();
  int b = blockIdx.y;
  int p = blockIdx.x * 256 + threadIdx.x;
  const float* ip = in + (size_t)b * NC * NP + p;
  float acc[16];
#pragma unroll
  for (int o = 0; o < 16; ++o) acc[o] = 0.f;
  for (int ci = 0; ci < NC; ++ci) {
    float xv = ip[(size_t)ci * NP];
#pragma unroll
    for (int o = 0; o < 16; ++o) acc[o] += xv * wl[o * NC + ci];
  }
  const float SC = 0.36067376022224085f;  // 0.25 * log2(e)
  short* op = Qb + ((size_t)b * NP + p) * 32;
#pragma unroll
  for (int o = 0; o < 16; ++o) op[o] = f2bf(acc[o] * SC);
#pragma unroll
  for (int o = 16; o < 32; ++o) op[o] = 0;
}

// ---------------- kv prep: 1x1 conv -> K[b][p][32] bf16 (d16-31=0), VT[b][16][p] bf16
__global__ __launch_bounds__(256) void kvprep_kernel(const float* __restrict__ in,
                                                     const float* __restrict__ w,
                                                     short* __restrict__ Kb,
                                                     short* __restrict__ VTb) {
  __shared__ float wl[32 * NC];
  for (int i = threadIdx.x; i < 32 * NC; i += 256) wl[i] = w[i];
  __syncthreads();
  int b = blockIdx.y;
  int p = blockIdx.x * 256 + threadIdx.x;
  const float* ip = in + (size_t)b * NC * NP + p;
  float acc[32];
#pragma unroll
  for (int o = 0; o < 32; ++o) acc[o] = 0.f;
  for (int ci = 0; ci < NC; ++ci) {
    float xv = ip[(size_t)ci * NP];
#pragma unroll
    for (int o = 0; o < 32; ++o) acc[o] += xv * wl[o * NC + ci];
  }
  short* kp = Kb + ((size_t)b * NP + p) * 32;
#pragma unroll
  for (int o = 0; o < 16; ++o) kp[o] = f2bf(acc[o]);
#pragma unroll
  for (int o = 16; o < 32; ++o) kp[o] = 0;
#pragma unroll
  for (int o = 0; o < 16; ++o)
    VTb[((size_t)b * 16 + o) * NP + p] = f2bf(acc[16 + o]);
}

// ---------------- MFMA flash attention ----------------
// grid (36, NB), 256 thr = 4 independent waves; wave handles 16 queries over all 2304 keys.
// Swapped QK^T: S^T = mfma(A=K-rows(permuted), B=Q^T). A-row permutation f0/f1 makes each
// lane hold exactly local keys 8g..8g+7 -> PV B-frag layout with NO cross-lane shuffle.
__global__ __launch_bounds__(256) void attn_mfma_kernel(const short* __restrict__ Qb,
                                                        const short* __restrict__ Kb,
                                                        const short* __restrict__ VTb,
                                                        float* __restrict__ out) {
  int b    = blockIdx.y;
  int lane = threadIdx.x & 63;
  int wave = threadIdx.x >> 6;
  int q0   = (blockIdx.x * 4 + wave) * 16;
  int g    = lane >> 4;
  int ql   = lane & 15;

  // Q B-frag: B[k=d=g*8+j][col=q=ql]
  s16x8 qfrag = *(const s16x8*)(Qb + ((size_t)b * NP + q0 + ql) * 32 + g * 8);

  // K A-row permutation: A-row rho holds key f0(rho); f0 = 8*(rho>>2)+(rho&3), f1 = f0+4
  int r0 = 8 * (ql >> 2) + (ql & 3);
  const short* Kbase = Kb + (size_t)b * NP * 32 + g * 8;
  const short* Vbase = VTb + ((size_t)b * 16 + ql) * NP;  // A-row = d = ql

  f32x4 acc = {0.f, 0.f, 0.f, 0.f};
  float m = -1e30f, l = 0.f;

  s16x8 kf0 = *(const s16x8*)(Kbase + (size_t)r0 * 32);
  s16x8 kf1 = *(const s16x8*)(Kbase + (size_t)(r0 + 4) * 32);
  s16x8 vf  = *(const s16x8*)(Vbase + g * 8);

  for (int step = 0; step < 72; ++step) {
    int k0n = (step < 71) ? (step + 1) * 32 : 0;   // wraparound dummy prefetch on last step
    s16x8 nk0 = *(const s16x8*)(Kbase + (size_t)(k0n + r0) * 32);
    s16x8 nk1 = *(const s16x8*)(Kbase + (size_t)(k0n + r0 + 4) * 32);
    s16x8 nv  = *(const s16x8*)(Vbase + k0n + g * 8);

    f32x4 z = {0.f, 0.f, 0.f, 0.f};
    f32x4 s0 = __builtin_amdgcn_mfma_f32_16x16x32_bf16(kf0, qfrag, z, 0, 0, 0);
    f32x4 s1 = __builtin_amdgcn_mfma_f32_16x16x32_bf16(kf1, qfrag, z, 0, 0, 0);
    // s0[r] = S[key 8g+r][q], s1[r] = S[key 8g+4+r][q]  (log2-scaled scores)

    float tm = fmaxf(fmaxf(fmaxf(s0[0], s0[1]), fmaxf(s0[2], s0[3])),
                     fmaxf(fmaxf(s1[0], s1[1]), fmaxf(s1[2], s1[3])));
    tm = fmaxf(tm, __shfl_xor(tm, 16, 64));
    tm = fmaxf(tm, __shfl_xor(tm, 32, 64));
    float mn = fmaxf(m, tm);
    float corr = exp2f(m - mn);
    m = mn;
    float p0 = exp2f(s0[0] - m), p1 = exp2f(s0[1] - m);
    float p2 = exp2f(s0[2] - m), p3 = exp2f(s0[3] - m);
    float p4 = exp2f(s1[0] - m), p5 = exp2f(s1[1] - m);
    float p6 = exp2f(s1[2] - m), p7 = exp2f(s1[3] - m);
    l = l * corr + ((p0 + p1) + (p2 + p3)) + ((p4 + p5) + (p6 + p7));
    acc[0] *= corr; acc[1] *= corr; acc[2] *= corr; acc[3] *= corr;

    s16x8 pf;
    pf[0] = f2bf(p0); pf[1] = f2bf(p1); pf[2] = f2bf(p2); pf[3] = f2bf(p3);
    pf[4] = f2bf(p4); pf[5] = f2bf(p5); pf[6] = f2bf(p6); pf[7] = f2bf(p7);
    acc = __builtin_amdgcn_mfma_f32_16x16x32_bf16(vf, pf, acc, 0, 0, 0);

    kf0 = nk0; kf1 = nk1; vf = nv;
  }
  l += __shfl_xor(l, 16, 64);
  l += __shfl_xor(l, 32, 64);
  float inv = 1.f / l;
  // lane holds out[q=q0+ql][d=4g+r] ; write to aobuf [b][16 d][2304 p]
  float* op = out + ((size_t)b * 16 + g * 4) * NP + q0 + ql;
  op[0]          = acc[0] * inv;
  op[NP]         = acc[1] * inv;
  op[2 * NP]     = acc[2] * inv;
  op[3 * NP]     = acc[3] * inv;
}

// ---------------- launch ----------------
extern "C" void kernel_launch(void* const* d_in, const int* in_sizes, int n_in,
                              void* d_out, int out_size, void* d_ws, size_t ws_size,
                              hipStream_t stream) {
  const float* x      = (const float*)d_in[0];
  const float* xe     = (const float*)d_in[1];
  const float* temb   = (const float*)d_in[2];
  const float* gn1w   = (const float*)d_in[3];
  const float* gn1b   = (const float*)d_in[4];
  const float* conv1w = (const float*)d_in[5];
  const float* conv1b = (const float*)d_in[6];
  const float* affw   = (const float*)d_in[7];
  const float* affb   = (const float*)d_in[8];
  const float* gn2w   = (const float*)d_in[9];
  const float* gn2b   = (const float*)d_in[10];
  const float* conv2w = (const float*)d_in[11];
  const float* conv2b = (const float*)d_in[12];
  const float* qw     = (const float*)d_in[13];
  const float* kvw    = (const float*)d_in[14];
  const float* outw   = (const float*)d_in[15];
  const float* outb   = (const float*)d_in[16];
  float* out = (float*)d_out;
  float* ws  = (float*)d_ws;

  // ws layout
  float* aobuf = ws;                                  // 294,912 f32
  float* gbsum = aobuf + (size_t)NB * 16 * NP;        // 1,536
  float* stats = gbsum + NB * NC;                     // 512
  float* wto   = stats + 512;                         // 27,648
  short* wbuf1 = (short*)(wto + (size_t)NC * NCQ * 9);        // 331,776 bf16
  short* wbuf2 = wbuf1 + (size_t)6 * 9 * 12 * 64 * 8;         // 331,776 bf16
  short* actt  = wbuf2 + (size_t)6 * 9 * 12 * 64 * 8;         // 3,993,600 bf16
  short* Qb    = actt + ACT_T_ELEMS;                          // 589,824 bf16
  short* Kb    = Qb + (size_t)NB * NP * 32;                   // 589,824 bf16
  short* VTb   = Kb + (size_t)NB * NP * 32;                   // 294,912 bf16

  // prep
  wprep_kernel<<<1296, 256, 0, stream>>>(conv1w, wbuf1);
  wprep_kernel<<<1296, 256, 0, stream>>>(conv2w, wbuf2);
  transpose_w_kernel<<<108, 256, 0, stream>>>(outw, wto, NC, NCQ);
  affine_kernel<<<6, 256, 0, stream>>>(temb, affw, affb, gbsum);
  hipMemsetAsync(actt, 0, ACT_T_ELEMS * sizeof(short), stream);

  // ----- ResnetBlock -----
  gn_stats_kernel<<<NB * NGROUPS, 256, 0, stream>>>(x, stats);
  gn_apply_t_kernel<<<NB * NH, 256, 0, stream>>>(x, stats, gn1w, gn1b, actt);
  conv_mfma_kernel<true, false><<<dim3(NB * 24, 3), 256, 0, stream>>>(
      actt, wbuf1, conv1b, gbsum, nullptr, out);
  gn_stats_kernel<<<NB * NGROUPS, 256, 0, stream>>>(out, stats);
  gn_apply_t_kernel<<<NB * NH, 256, 0, stream>>>(out, stats, gn2w, gn2b, actt);
  conv_mfma_kernel<false, true><<<dim3(NB * 24, 3), 256, 0, stream>>>(
      actt, wbuf2, conv2b, nullptr, x, out);

  // ----- CrossAttention -----
  qprep_kernel<<<dim3(9, NB), 256, 0, stream>>>(out, qw, Qb);
  kvprep_kernel<<<dim3(9, NB), 256, 0, stream>>>(xe, kvw, Kb, VTb);
  attn_mfma_kernel<<<dim3(36, NB), 256, 0, stream>>>(Qb, Kb, VTb, aobuf);
  conv3x3_kernel<NCQ, 16, false, true><<<dim3(NB * NH, 3), 256, 0, stream>>>(
      aobuf, wto, outb, nullptr, out, out, NC);
}

// Round 5
// 352.460 us; speedup vs baseline: 2.9737x; 1.1030x over previous
//
#include <hip/hip_runtime.h>
#include <hip/hip_bf16.h>

#define NB 8
#define NC 192
#define NH 48
#define NW 48
#define NP 2304        // 48*48
#define NGROUPS 32
#define CPG 6          // NC/NGROUPS
#define NEMB 192
#define NCQ 16

// padded-transposed activation: [B][50 h'][52 w' stride (50 used)][192 c] bf16
#define PH 50
#define PWS 52
#define ACT_T_ELEMS ((size_t)NB * PH * PWS * NC)   // 3,993,600 bf16

typedef __attribute__((ext_vector_type(4))) short s16x4;
typedef __attribute__((ext_vector_type(8))) short s16x8;
typedef __attribute__((ext_vector_type(4))) float f32x4;

static __device__ inline short f2bf(float v) {
  __hip_bfloat16 h = __float2bfloat16(v);
  return *(short*)&h;
}

// ---------------- weight transpose (out conv only): w[co][ci][k] -> wt[(ci*9+k)*CO+co]
__global__ __launch_bounds__(256) void transpose_w_kernel(const float* __restrict__ w,
                                                          float* __restrict__ wt,
                                                          int CO, int CI) {
  int i = blockIdx.x * 256 + threadIdx.x;
  int total = CO * CI * 9;
  if (i >= total) return;
  int co = i / (CI * 9);
  int rem = i - co * (CI * 9);
  wt[rem * CO + co] = w[i];
}

// ---------------- MFMA weight prep: wbuf[kc(6)][t(9)][cf(12)][lane(64)][j(8)] bf16
__global__ __launch_bounds__(256) void wprep_kernel(const float* __restrict__ w,
                                                    short* __restrict__ wbuf) {
  int i = blockIdx.x * 256 + threadIdx.x;
  if (i >= 6 * 9 * 12 * 64 * 8) return;
  int j  = i & 7;
  int l  = (i >> 3) & 63;
  int cf = (i >> 9) % 12;
  int tk = (i >> 9) / 12;      // kc*9 + t
  int t  = tk % 9;
  int kc = tk / 9;
  int co = cf * 16 + (l & 15);
  int ci = kc * 32 + (l >> 4) * 8 + j;
  wbuf[i] = f2bf(w[((size_t)co * NC + ci) * 9 + t]);
}

// ---------------- FeatureWiseAffine GEMV ----------------
__global__ __launch_bounds__(256) void affine_kernel(const float* __restrict__ emb,
                                                     const float* __restrict__ aw,
                                                     const float* __restrict__ ab,
                                                     float* __restrict__ gbsum) {
  int i = blockIdx.x * 256 + threadIdx.x;
  if (i >= NB * NC) return;
  int b = i / NC;
  int c = i - b * NC;
  const float* e  = emb + b * NEMB;
  const float* w0 = aw + c * NEMB;
  const float* w1 = aw + (c + NC) * NEMB;
  float s = 0.f;
  for (int j = 0; j < NEMB; ++j) s += e[j] * (w0[j] + w1[j]);
  gbsum[i] = 0.5f * (s + ab[c] + ab[c + NC]);
}

// ---------------- halo zero for actt (replaces 8MB memset) ----------------
__global__ __launch_bounds__(256) void halo_zero_kernel(short* __restrict__ actt) {
  int b = blockIdx.y;
  int i = blockIdx.x * 256 + threadIdx.x;   // short4 granules; 9600 per b
  if (i >= 9600) return;
  int c4 = i % 48;
  int r  = i / 48;                          // 0..199
  size_t off;
  if (r < 52)       off = ((size_t)0 * PWS + r) * NC;              // row 0 (all cols)
  else if (r < 104) off = ((size_t)49 * PWS + (r - 52)) * NC;      // row 49
  else if (r < 152) off = ((size_t)(r - 104 + 1) * PWS + 0) * NC;  // col 0, rows 1..48
  else              off = ((size_t)(r - 152 + 1) * PWS + 49) * NC; // col 49
  *(s16x4*)(&actt[(size_t)b * PH * PWS * NC + off + c4 * 4]) = (s16x4){0, 0, 0, 0};
}

// ---------------- GroupNorm stats ----------------
__global__ __launch_bounds__(256) void gn_stats_kernel(const float* __restrict__ in,
                                                       float* __restrict__ stats) {
  int bg = blockIdx.x;
  const float4* p = (const float4*)(in + (size_t)bg * (CPG * NP));
  float s = 0.f, s2 = 0.f;
  for (int i = threadIdx.x; i < CPG * NP / 4; i += 256) {
    float4 v = p[i];
    s  += v.x + v.y + v.z + v.w;
    s2 += v.x * v.x + v.y * v.y + v.z * v.z + v.w * v.w;
  }
#pragma unroll
  for (int off = 32; off > 0; off >>= 1) {
    s  += __shfl_down(s, off);
    s2 += __shfl_down(s2, off);
  }
  __shared__ float red[8];
  int wave = threadIdx.x >> 6;
  if ((threadIdx.x & 63) == 0) { red[wave * 2] = s; red[wave * 2 + 1] = s2; }
  __syncthreads();
  if (threadIdx.x == 0) {
    float S  = red[0] + red[2] + red[4] + red[6];
    float S2 = red[1] + red[3] + red[5] + red[7];
    const float invN = 1.f / (float)(CPG * NP);
    float mean = S * invN;
    float var  = S2 * invN - mean * mean;
    stats[bg * 2]     = mean;
    stats[bg * 2 + 1] = rsqrtf(var + 1e-5f);
  }
}

// ---------------- GN apply + swish -> padded TRANSPOSED bf16 act_t ----------------
__global__ __launch_bounds__(256) void gn_apply_t_kernel(const float* __restrict__ in,
                                                         const float* __restrict__ stats,
                                                         const float* __restrict__ gw,
                                                         const float* __restrict__ gb,
                                                         short* __restrict__ actt) {
  __shared__ float tile[48 * 193];
  int bh = blockIdx.x;
  int b = bh / NH;
  int h = bh - b * NH;
  int tid = threadIdx.x;
  for (int i = tid; i < 2304; i += 256) {
    int c = i / 12;
    int w = (i % 12) * 4;
    float4 v = *(const float4*)(in + (((size_t)b * NC + c) * NH + h) * NW + w);
    float mean = stats[(b * NGROUPS + c / CPG) * 2];
    float rstd = stats[(b * NGROUPS + c / CPG) * 2 + 1];
    float sc = rstd * gw[c];
    float sh = gb[c] - mean * sc;
    float y;
    y = v.x * sc + sh; tile[(w + 0) * 193 + c] = y / (1.f + __expf(-y));
    y = v.y * sc + sh; tile[(w + 1) * 193 + c] = y / (1.f + __expf(-y));
    y = v.z * sc + sh; tile[(w + 2) * 193 + c] = y / (1.f + __expf(-y));
    y = v.w * sc + sh; tile[(w + 3) * 193 + c] = y / (1.f + __expf(-y));
  }
  __syncthreads();
  short* dst = actt + (((size_t)b * PH + h + 1) * PWS + 1) * NC;
  for (int i = tid; i < 2304; i += 256) {
    int w  = i / 48;
    int c4 = (i - w * 48) * 4;
    s16x4 o;
    o.x = f2bf(tile[w * 193 + c4 + 0]);
    o.y = f2bf(tile[w * 193 + c4 + 1]);
    o.z = f2bf(tile[w * 193 + c4 + 2]);
    o.w = f2bf(tile[w * 193 + c4 + 3]);
    *(s16x4*)(dst + (size_t)w * NC + c4) = o;
  }
}

// ---------------- conv3x3 via MFMA (tap-decomposed implicit GEMM) ----------------
template <bool AFFINE, bool RESID>
__global__ __launch_bounds__(256) void conv_mfma_kernel(const short* __restrict__ actt,
                                                        const short* __restrict__ wbuf,
                                                        const float* __restrict__ bias,
                                                        const float* __restrict__ gbsum,
                                                        const float* __restrict__ resid,
                                                        float* __restrict__ out) {
  __shared__ short S[4][50][40];
  int bs = blockIdx.x;
  int b = bs / 24;
  int strip = bs - b * 24;
  int coB = blockIdx.y;
  int h0 = strip * 2;
  int tid = threadIdx.x;
  int lane = tid & 63, wave = tid >> 6;
  int wy = wave >> 1, wx = wave & 1;
  int g8 = (lane >> 4) * 8;

  f32x4 acc[2][3];
#pragma unroll
  for (int m = 0; m < 2; ++m)
#pragma unroll
    for (int f = 0; f < 3; ++f) acc[m][f] = (f32x4){0.f, 0.f, 0.f, 0.f};

  const size_t actbase = ((size_t)b * PH + h0) * PWS * NC;

  for (int kc = 0; kc < 6; ++kc) {
    __syncthreads();
    for (int i = tid; i < 800; i += 256) {
      int ci8 = i & 3;
      int rc  = i >> 2;
      int col = rc % 50, r = rc / 50;
      const s16x8* src = (const s16x8*)(actt + actbase + ((size_t)r * PWS + col) * NC +
                                        kc * 32 + ci8 * 8);
      *(s16x8*)(&S[r][col][ci8 * 8]) = *src;
    }
    __syncthreads();
#pragma unroll
    for (int t = 0; t < 9; ++t) {
      int ky = t / 3, kx = t - ky * 3;
      const short* wp = wbuf + ((((size_t)kc * 9 + t) * 12 + (coB * 4 + wy * 2)) * 64 + lane) * 8;
      s16x8 a0 = *(const s16x8*)wp;
      s16x8 a1 = *(const s16x8*)(wp + 64 * 8);
      int row = wx + ky;
#pragma unroll
      for (int f = 0; f < 3; ++f) {
        int col = f * 16 + (lane & 15) + kx;
        s16x8 bf = *(const s16x8*)(&S[row][col][g8]);
        acc[0][f] = __builtin_amdgcn_mfma_f32_16x16x32_bf16(a0, bf, acc[0][f], 0, 0, 0);
        acc[1][f] = __builtin_amdgcn_mfma_f32_16x16x32_bf16(a1, bf, acc[1][f], 0, 0, 0);
      }
    }
  }
  int hout = h0 + wx;
#pragma unroll
  for (int m = 0; m < 2; ++m) {
    int co0 = coB * 64 + wy * 32 + m * 16;
#pragma unroll
    for (int r = 0; r < 4; ++r) {
      int co = co0 + (lane >> 4) * 4 + r;
      float bv = bias[co];
      float s = AFFINE ? gbsum[b * NC + co] : 0.f;
#pragma unroll
      for (int f = 0; f < 3; ++f) {
        int w = f * 16 + (lane & 15);
        size_t o = (((size_t)b * NC + co) * NH + hout) * NW + w;
        float v = acc[m][f][r] + bv;
        if (AFFINE) v = v * (1.f + s) + s;
        if (RESID) v += resid[o];
        out[o] = v;
      }
    }
  }
}

// ---------------- direct 3x3 conv (small CI; used for out conv) ----------------
template <int CI, int CICHUNK, bool AFFINE, bool RESID>
__global__ __launch_bounds__(256) void conv3x3_kernel(const float* __restrict__ in,
                                                      const float* __restrict__ wt,
                                                      const float* __restrict__ bias,
                                                      const float* __restrict__ gbsum,
                                                      const float* resid,
                                                      float* out, int CO) {
  __shared__ float lds[CICHUNK][3][52];
  int bh = blockIdx.x;
  int b = bh / NH;
  int h = bh - b * NH;
  int co = blockIdx.y * 64 + (threadIdx.x & 63);
  int wq = threadIdx.x >> 6;
  int wb = wq * 12;
  float acc[12];
#pragma unroll
  for (int i = 0; i < 12; ++i) acc[i] = 0.f;

  for (int ci0 = 0; ci0 < CI; ci0 += CICHUNK) {
    __syncthreads();
    for (int i = threadIdx.x; i < CICHUNK * 150; i += 256) {
      int ci  = i / 150;
      int rem = i - ci * 150;
      int r   = rem / 50;
      int col = rem - r * 50;
      int hh  = h - 1 + r;
      int ww  = col - 1;
      float v = 0.f;
      if (hh >= 0 && hh < NH && (unsigned)ww < (unsigned)NW)
        v = in[((b * CI + ci0 + ci) * NH + hh) * NW + ww];
      lds[ci][r][col] = v;
    }
    __syncthreads();
    for (int ci = 0; ci < CICHUNK; ++ci) {
      float wk[9];
      const float* wp = wt + (size_t)(ci0 + ci) * 9 * CO + co;
#pragma unroll
      for (int k = 0; k < 9; ++k) wk[k] = wp[k * CO];
#pragma unroll
      for (int r = 0; r < 3; ++r) {
        float v[14];
#pragma unroll
        for (int t = 0; t < 14; ++t) v[t] = lds[ci][r][wb + t];
#pragma unroll
        for (int w = 0; w < 12; ++w)
          acc[w] += v[w] * wk[r * 3] + v[w + 1] * wk[r * 3 + 1] + v[w + 2] * wk[r * 3 + 2];
      }
    }
  }
  float bv = bias[co];
  float sfa = 0.f;
  if (AFFINE) sfa = gbsum[b * CO + co];
  int base = ((b * CO + co) * NH + h) * NW + wb;
#pragma unroll
  for (int w = 0; w < 12; ++w) {
    float v = acc[w] + bv;
    if (AFFINE) v = v * (1.f + sfa) + sfa;
    if (RESID) v += resid[base + w];
    out[base + w] = v;
  }
}

// ---------------- split-K 1x1-conv partials: part[ch][b][o][p] ----------------
// grid (NP/256, 3, NB); each block: 64 ci, 256 px, weights in LDS (broadcast reads).
template <int NOUT>
__global__ __launch_bounds__(256) void prep_partial_kernel(const float* __restrict__ X,
                                                           const float* __restrict__ W,
                                                           float* __restrict__ part) {
  __shared__ float wl[NOUT][64];
  int pt = blockIdx.x, ch = blockIdx.y, b = blockIdx.z;
  for (int i = threadIdx.x; i < NOUT * 64; i += 256) {
    int o = i >> 6, c = i & 63;
    wl[o][c] = W[o * NC + ch * 64 + c];
  }
  __syncthreads();
  int p = pt * 256 + threadIdx.x;
  const float* ip = X + ((size_t)b * NC + ch * 64) * NP + p;
  float acc[NOUT];
#pragma unroll
  for (int o = 0; o < NOUT; ++o) acc[o] = 0.f;
#pragma unroll 8
  for (int ci = 0; ci < 64; ++ci) {
    float xv = ip[(size_t)ci * NP];
#pragma unroll
    for (int o = 0; o < NOUT; ++o) acc[o] += xv * wl[o][ci];
  }
  float* op = part + ((size_t)(ch * NB + b) * NOUT) * NP + p;
#pragma unroll
  for (int o = 0; o < NOUT; ++o) op[(size_t)o * NP] = acc[o];
}

// ---------------- pack: partials -> Qb[p][32] (scaled, zero-pad), Kb[p][32], VTb[16][p]
__global__ __launch_bounds__(256) void prep_pack_kernel(const float* __restrict__ pq,
                                                        const float* __restrict__ pkv,
                                                        short* __restrict__ Qb,
                                                        short* __restrict__ Kb,
                                                        short* __restrict__ VTb) {
  __shared__ short QL[16][264], KL[16][264];
  int pt = blockIdx.x, b = blockIdx.y;
  int tp = threadIdx.x;
  int p  = pt * 256 + tp;
  const float SC = 0.36067376022224085f;  // 0.25 * log2(e)
#pragma unroll
  for (int o = 0; o < 16; ++o) {
    float s = pq[((size_t)(0 * NB + b) * 16 + o) * NP + p] +
              pq[((size_t)(1 * NB + b) * 16 + o) * NP + p] +
              pq[((size_t)(2 * NB + b) * 16 + o) * NP + p];
    QL[o][tp] = f2bf(s * SC);
  }
#pragma unroll
  for (int o = 0; o < 32; ++o) {
    float s = pkv[((size_t)(0 * NB + b) * 32 + o) * NP + p] +
              pkv[((size_t)(1 * NB + b) * 32 + o) * NP + p] +
              pkv[((size_t)(2 * NB + b) * 32 + o) * NP + p];
    if (o < 16) KL[o][tp] = f2bf(s);
    else VTb[((size_t)b * 16 + (o - 16)) * NP + p] = f2bf(s);
  }
  __syncthreads();
  short* qp = Qb + ((size_t)b * NP + p) * 32;
  short* kp = Kb + ((size_t)b * NP + p) * 32;
#pragma unroll
  for (int o4 = 0; o4 < 4; ++o4) {
    s16x4 vq = {QL[o4 * 4 + 0][tp], QL[o4 * 4 + 1][tp], QL[o4 * 4 + 2][tp], QL[o4 * 4 + 3][tp]};
    s16x4 vk = {KL[o4 * 4 + 0][tp], KL[o4 * 4 + 1][tp], KL[o4 * 4 + 2][tp], KL[o4 * 4 + 3][tp]};
    *(s16x4*)(qp + o4 * 4) = vq;
    *(s16x4*)(kp + o4 * 4) = vk;
    *(s16x4*)(qp + 16 + o4 * 4) = (s16x4){0, 0, 0, 0};
    *(s16x4*)(kp + 16 + o4 * 4) = (s16x4){0, 0, 0, 0};
  }
}

// ---------------- MFMA flash attention ----------------
__global__ __launch_bounds__(256) void attn_mfma_kernel(const short* __restrict__ Qb,
                                                        const short* __restrict__ Kb,
                                                        const short* __restrict__ VTb,
                                                        float* __restrict__ out) {
  int b    = blockIdx.y;
  int lane = threadIdx.x & 63;
  int wave = threadIdx.x >> 6;
  int q0   = (blockIdx.x * 4 + wave) * 16;
  int g    = lane >> 4;
  int ql   = lane & 15;

  s16x8 qfrag = *(const s16x8*)(Qb + ((size_t)b * NP + q0 + ql) * 32 + g * 8);

  int r0 = 8 * (ql >> 2) + (ql & 3);
  const short* Kbase = Kb + (size_t)b * NP * 32 + g * 8;
  const short* Vbase = VTb + ((size_t)b * 16 + ql) * NP;

  f32x4 acc = {0.f, 0.f, 0.f, 0.f};
  float m = -1e30f, l = 0.f;

  s16x8 kf0 = *(const s16x8*)(Kbase + (size_t)r0 * 32);
  s16x8 kf1 = *(const s16x8*)(Kbase + (size_t)(r0 + 4) * 32);
  s16x8 vf  = *(const s16x8*)(Vbase + g * 8);

  for (int step = 0; step < 72; ++step) {
    int k0n = (step < 71) ? (step + 1) * 32 : 0;
    s16x8 nk0 = *(const s16x8*)(Kbase + (size_t)(k0n + r0) * 32);
    s16x8 nk1 = *(const s16x8*)(Kbase + (size_t)(k0n + r0 + 4) * 32);
    s16x8 nv  = *(const s16x8*)(Vbase + k0n + g * 8);

    f32x4 z = {0.f, 0.f, 0.f, 0.f};
    f32x4 s0 = __builtin_amdgcn_mfma_f32_16x16x32_bf16(kf0, qfrag, z, 0, 0, 0);
    f32x4 s1 = __builtin_amdgcn_mfma_f32_16x16x32_bf16(kf1, qfrag, z, 0, 0, 0);

    float tm = fmaxf(fmaxf(fmaxf(s0[0], s0[1]), fmaxf(s0[2], s0[3])),
                     fmaxf(fmaxf(s1[0], s1[1]), fmaxf(s1[2], s1[3])));
    tm = fmaxf(tm, __shfl_xor(tm, 16, 64));
    tm = fmaxf(tm, __shfl_xor(tm, 32, 64));
    float mn = fmaxf(m, tm);
    float corr = exp2f(m - mn);
    m = mn;
    float p0 = exp2f(s0[0] - m), p1 = exp2f(s0[1] - m);
    float p2 = exp2f(s0[2] - m), p3 = exp2f(s0[3] - m);
    float p4 = exp2f(s1[0] - m), p5 = exp2f(s1[1] - m);
    float p6 = exp2f(s1[2] - m), p7 = exp2f(s1[3] - m);
    l = l * corr + ((p0 + p1) + (p2 + p3)) + ((p4 + p5) + (p6 + p7));
    acc[0] *= corr; acc[1] *= corr; acc[2] *= corr; acc[3] *= corr;

    s16x8 pf;
    pf[0] = f2bf(p0); pf[1] = f2bf(p1); pf[2] = f2bf(p2); pf[3] = f2bf(p3);
    pf[4] = f2bf(p4); pf[5] = f2bf(p5); pf[6] = f2bf(p6); pf[7] = f2bf(p7);
    acc = __builtin_amdgcn_mfma_f32_16x16x32_bf16(vf, pf, acc, 0, 0, 0);

    kf0 = nk0; kf1 = nk1; vf = nv;
  }
  l += __shfl_xor(l, 16, 64);
  l += __shfl_xor(l, 32, 64);
  float inv = 1.f / l;
  float* op = out + ((size_t)b * 16 + g * 4) * NP + q0 + ql;
  op[0]      = acc[0] * inv;
  op[NP]     = acc[1] * inv;
  op[2 * NP] = acc[2] * inv;
  op[3 * NP] = acc[3] * inv;
}

// ---------------- launch ----------------
extern "C" void kernel_launch(void* const* d_in, const int* in_sizes, int n_in,
                              void* d_out, int out_size, void* d_ws, size_t ws_size,
                              hipStream_t stream) {
  const float* x      = (const float*)d_in[0];
  const float* xe     = (const float*)d_in[1];
  const float* temb   = (const float*)d_in[2];
  const float* gn1w   = (const float*)d_in[3];
  const float* gn1b   = (const float*)d_in[4];
  const float* conv1w = (const float*)d_in[5];
  const float* conv1b = (const float*)d_in[6];
  const float* affw   = (const float*)d_in[7];
  const float* affb   = (const float*)d_in[8];
  const float* gn2w   = (const float*)d_in[9];
  const float* gn2b   = (const float*)d_in[10];
  const float* conv2w = (const float*)d_in[11];
  const float* conv2b = (const float*)d_in[12];
  const float* qw     = (const float*)d_in[13];
  const float* kvw    = (const float*)d_in[14];
  const float* outw   = (const float*)d_in[15];
  const float* outb   = (const float*)d_in[16];
  float* out = (float*)d_out;
  float* ws  = (float*)d_ws;

  // ws layout (f32 region first, then bf16 region)
  float* aobuf  = ws;                                    // 294,912 f32
  float* gbsum  = aobuf + (size_t)NB * 16 * NP;          // 1,536
  float* stats  = gbsum + NB * NC;                       // 512
  float* wto    = stats + 512;                           // 27,648
  float* partQ  = wto + (size_t)NC * NCQ * 9;            // 3*8*16*NP = 884,736
  float* partKV = partQ + (size_t)3 * NB * 16 * NP;      // 3*8*32*NP = 1,769,472
  short* wbuf1  = (short*)(partKV + (size_t)3 * NB * 32 * NP);  // 331,776 bf16
  short* wbuf2  = wbuf1 + (size_t)6 * 9 * 12 * 64 * 8;          // 331,776 bf16
  short* actt   = wbuf2 + (size_t)6 * 9 * 12 * 64 * 8;          // 3,993,600 bf16
  short* Qb     = actt + ACT_T_ELEMS;                           // 589,824 bf16
  short* Kb     = Qb + (size_t)NB * NP * 32;                    // 589,824 bf16
  short* VTb    = Kb + (size_t)NB * NP * 32;                    // 294,912 bf16

  // prep
  wprep_kernel<<<1296, 256, 0, stream>>>(conv1w, wbuf1);
  wprep_kernel<<<1296, 256, 0, stream>>>(conv2w, wbuf2);
  transpose_w_kernel<<<108, 256, 0, stream>>>(outw, wto, NC, NCQ);
  affine_kernel<<<6, 256, 0, stream>>>(temb, affw, affb, gbsum);
  halo_zero_kernel<<<dim3(38, NB), 256, 0, stream>>>(actt);
  // kv prep is independent of the resnet chain — run it early
  prep_partial_kernel<32><<<dim3(9, 3, NB), 256, 0, stream>>>(xe, kvw, partKV);

  // ----- ResnetBlock -----
  gn_stats_kernel<<<NB * NGROUPS, 256, 0, stream>>>(x, stats);
  gn_apply_t_kernel<<<NB * NH, 256, 0, stream>>>(x, stats, gn1w, gn1b, actt);
  conv_mfma_kernel<true, false><<<dim3(NB * 24, 3), 256, 0, stream>>>(
      actt, wbuf1, conv1b, gbsum, nullptr, out);
  gn_stats_kernel<<<NB * NGROUPS, 256, 0, stream>>>(out, stats);
  gn_apply_t_kernel<<<NB * NH, 256, 0, stream>>>(out, stats, gn2w, gn2b, actt);
  conv_mfma_kernel<false, true><<<dim3(NB * 24, 3), 256, 0, stream>>>(
      actt, wbuf2, conv2b, nullptr, x, out);

  // ----- CrossAttention -----
  prep_partial_kernel<16><<<dim3(9, 3, NB), 256, 0, stream>>>(out, qw, partQ);
  prep_pack_kernel<<<dim3(9, NB), 256, 0, stream>>>(partQ, partKV, Qb, Kb, VTb);
  attn_mfma_kernel<<<dim3(36, NB), 256, 0, stream>>>(Qb, Kb, VTb, aobuf);
  conv3x3_kernel<NCQ, 16, false, true><<<dim3(NB * NH, 3), 256, 0, stream>>>(
      aobuf, wto, outb, nullptr, out, out, NC);
}

// Round 6
// 308.255 us; speedup vs baseline: 3.4002x; 1.1434x over previous
//
#include <hip/hip_runtime.h>
#include <hip/hip_bf16.h>

#define NB 8
#define NC 192
#define NH 48
#define NW 48
#define NP 2304        // 48*48
#define NGROUPS 32
#define CPG 6          // NC/NGROUPS
#define NEMB 192
#define NCQ 16

// padded-transposed activation: [B][50 h'][52 w' stride (50 used)][192 c] bf16
#define PH 50
#define PWS 52
#define ACT_T_ELEMS ((size_t)NB * PH * PWS * NC)   // 3,993,600 bf16
#define AOT_ELEMS   ((size_t)NB * PH * PWS * 16)   // 332,800 bf16

typedef __attribute__((ext_vector_type(4))) short s16x4;
typedef __attribute__((ext_vector_type(8))) short s16x8;
typedef __attribute__((ext_vector_type(4))) float f32x4;

static __device__ inline short f2bf(float v) {
  __hip_bfloat16 h = __float2bfloat16(v);
  return *(short*)&h;
}

// ---------------- MFMA weight prep (conv1/conv2): wbuf[kc6][t9][cf12][lane64][j8] bf16
__global__ __launch_bounds__(256) void wprep_kernel(const float* __restrict__ w,
                                                    short* __restrict__ wbuf) {
  int i = blockIdx.x * 256 + threadIdx.x;
  if (i >= 6 * 9 * 12 * 64 * 8) return;
  int j  = i & 7;
  int l  = (i >> 3) & 63;
  int cf = (i >> 9) % 12;
  int tk = (i >> 9) / 12;      // kc*9 + t
  int t  = tk % 9;
  int kc = tk / 9;
  int co = cf * 16 + (l & 15);
  int ci = kc * 32 + (l >> 4) * 8 + j;
  wbuf[i] = f2bf(w[((size_t)co * NC + ci) * 9 + t]);
}

// ---------------- MFMA weight prep (out conv, CI=16 padded to 32): wbuf_o[t9][cf12][l64][j8]
__global__ __launch_bounds__(256) void wprep_o_kernel(const float* __restrict__ w,
                                                      short* __restrict__ wbuf) {
  int i = blockIdx.x * 256 + threadIdx.x;
  if (i >= 9 * 12 * 64 * 8) return;
  int j  = i & 7;
  int l  = (i >> 3) & 63;
  int cf = (i >> 9) % 12;
  int t  = (i >> 9) / 12;
  int co = cf * 16 + (l & 15);
  int ci = (l >> 4) * 8 + j;   // 0..31; real for ci<16
  wbuf[i] = (ci < 16) ? f2bf(w[((size_t)co * 16 + ci) * 9 + t]) : (short)0;
}

// ---------------- FeatureWiseAffine GEMV ----------------
__global__ __launch_bounds__(256) void affine_kernel(const float* __restrict__ emb,
                                                     const float* __restrict__ aw,
                                                     const float* __restrict__ ab,
                                                     float* __restrict__ gbsum) {
  int i = blockIdx.x * 256 + threadIdx.x;
  if (i >= NB * NC) return;
  int b = i / NC;
  int c = i - b * NC;
  const float* e  = emb + b * NEMB;
  const float* w0 = aw + c * NEMB;
  const float* w1 = aw + (c + NC) * NEMB;
  float s = 0.f;
  for (int j = 0; j < NEMB; ++j) s += e[j] * (w0[j] + w1[j]);
  gbsum[i] = 0.5f * (s + ab[c] + ab[c + NC]);
}

// ---------------- halo zero for actt ----------------
__global__ __launch_bounds__(256) void halo_zero_kernel(short* __restrict__ actt) {
  int b = blockIdx.y;
  int i = blockIdx.x * 256 + threadIdx.x;   // short4 granules; 9600 per b
  if (i >= 9600) return;
  int c4 = i % 48;
  int r  = i / 48;                          // 0..199
  size_t off;
  if (r < 52)       off = ((size_t)0 * PWS + r) * NC;
  else if (r < 104) off = ((size_t)49 * PWS + (r - 52)) * NC;
  else if (r < 152) off = ((size_t)(r - 104 + 1) * PWS + 0) * NC;
  else              off = ((size_t)(r - 152 + 1) * PWS + 49) * NC;
  *(s16x4*)(&actt[(size_t)b * PH * PWS * NC + off + c4 * 4]) = (s16x4){0, 0, 0, 0};
}

// ---------------- halo zero for aobuf_t (16 ch) ----------------
__global__ __launch_bounds__(256) void halo_zero16_kernel(short* __restrict__ aot) {
  int b = blockIdx.x;
  for (int i = threadIdx.x; i < 784; i += 256) {  // 196 positions x 4 granules
    int c4  = i & 3;
    int pos = i >> 2;
    int r, col;
    if (pos < 50)       { r = 0;  col = pos; }
    else if (pos < 100) { r = 49; col = pos - 50; }
    else if (pos < 148) { r = pos - 100 + 1; col = 0; }
    else                { r = pos - 148 + 1; col = 49; }
    *(s16x4*)(&aot[(((size_t)b * PH + r) * PWS + col) * 16 + c4 * 4]) = (s16x4){0, 0, 0, 0};
  }
}

// ---------------- GroupNorm stats ----------------
__global__ __launch_bounds__(256) void gn_stats_kernel(const float* __restrict__ in,
                                                       float* __restrict__ stats) {
  int bg = blockIdx.x;
  const float4* p = (const float4*)(in + (size_t)bg * (CPG * NP));
  float s = 0.f, s2 = 0.f;
  for (int i = threadIdx.x; i < CPG * NP / 4; i += 256) {
    float4 v = p[i];
    s  += v.x + v.y + v.z + v.w;
    s2 += v.x * v.x + v.y * v.y + v.z * v.z + v.w * v.w;
  }
#pragma unroll
  for (int off = 32; off > 0; off >>= 1) {
    s  += __shfl_down(s, off);
    s2 += __shfl_down(s2, off);
  }
  __shared__ float red[8];
  int wave = threadIdx.x >> 6;
  if ((threadIdx.x & 63) == 0) { red[wave * 2] = s; red[wave * 2 + 1] = s2; }
  __syncthreads();
  if (threadIdx.x == 0) {
    float S  = red[0] + red[2] + red[4] + red[6];
    float S2 = red[1] + red[3] + red[5] + red[7];
    const float invN = 1.f / (float)(CPG * NP);
    float mean = S * invN;
    float var  = S2 * invN - mean * mean;
    stats[bg * 2]     = mean;
    stats[bg * 2 + 1] = rsqrtf(var + 1e-5f);
  }
}

// ---------------- GN apply + swish -> padded TRANSPOSED bf16 act_t ----------------
__global__ __launch_bounds__(256) void gn_apply_t_kernel(const float* __restrict__ in,
                                                         const float* __restrict__ stats,
                                                         const float* __restrict__ gw,
                                                         const float* __restrict__ gb,
                                                         short* __restrict__ actt) {
  __shared__ float tile[48 * 193];
  int bh = blockIdx.x;
  int b = bh / NH;
  int h = bh - b * NH;
  int tid = threadIdx.x;
  for (int i = tid; i < 2304; i += 256) {
    int c = i / 12;
    int w = (i % 12) * 4;
    float4 v = *(const float4*)(in + (((size_t)b * NC + c) * NH + h) * NW + w);
    float mean = stats[(b * NGROUPS + c / CPG) * 2];
    float rstd = stats[(b * NGROUPS + c / CPG) * 2 + 1];
    float sc = rstd * gw[c];
    float sh = gb[c] - mean * sc;
    float y;
    y = v.x * sc + sh; tile[(w + 0) * 193 + c] = y / (1.f + __expf(-y));
    y = v.y * sc + sh; tile[(w + 1) * 193 + c] = y / (1.f + __expf(-y));
    y = v.z * sc + sh; tile[(w + 2) * 193 + c] = y / (1.f + __expf(-y));
    y = v.w * sc + sh; tile[(w + 3) * 193 + c] = y / (1.f + __expf(-y));
  }
  __syncthreads();
  short* dst = actt + (((size_t)b * PH + h + 1) * PWS + 1) * NC;
  for (int i = tid; i < 2304; i += 256) {
    int w  = i / 48;
    int c4 = (i - w * 48) * 4;
    s16x4 o;
    o.x = f2bf(tile[w * 193 + c4 + 0]);
    o.y = f2bf(tile[w * 193 + c4 + 1]);
    o.z = f2bf(tile[w * 193 + c4 + 2]);
    o.w = f2bf(tile[w * 193 + c4 + 3]);
    *(s16x4*)(dst + (size_t)w * NC + c4) = o;
  }
}

// ---------------- conv3x3 via MFMA (tap-decomposed implicit GEMM), CI=192 ----------------
template <bool AFFINE, bool RESID>
__global__ __launch_bounds__(256) void conv_mfma_kernel(const short* __restrict__ actt,
                                                        const short* __restrict__ wbuf,
                                                        const float* __restrict__ bias,
                                                        const float* __restrict__ gbsum,
                                                        const float* __restrict__ resid,
                                                        float* __restrict__ out) {
  __shared__ short S[4][50][40];
  int bs = blockIdx.x;
  int b = bs / 24;
  int strip = bs - b * 24;
  int coB = blockIdx.y;
  int h0 = strip * 2;
  int tid = threadIdx.x;
  int lane = tid & 63, wave = tid >> 6;
  int wy = wave >> 1, wx = wave & 1;
  int g8 = (lane >> 4) * 8;

  f32x4 acc[2][3];
#pragma unroll
  for (int m = 0; m < 2; ++m)
#pragma unroll
    for (int f = 0; f < 3; ++f) acc[m][f] = (f32x4){0.f, 0.f, 0.f, 0.f};

  const size_t actbase = ((size_t)b * PH + h0) * PWS * NC;

  for (int kc = 0; kc < 6; ++kc) {
    __syncthreads();
    for (int i = tid; i < 800; i += 256) {
      int ci8 = i & 3;
      int rc  = i >> 2;
      int col = rc % 50, r = rc / 50;
      const s16x8* src = (const s16x8*)(actt + actbase + ((size_t)r * PWS + col) * NC +
                                        kc * 32 + ci8 * 8);
      *(s16x8*)(&S[r][col][ci8 * 8]) = *src;
    }
    __syncthreads();
#pragma unroll
    for (int t = 0; t < 9; ++t) {
      int ky = t / 3, kx = t - ky * 3;
      const short* wp = wbuf + ((((size_t)kc * 9 + t) * 12 + (coB * 4 + wy * 2)) * 64 + lane) * 8;
      s16x8 a0 = *(const s16x8*)wp;
      s16x8 a1 = *(const s16x8*)(wp + 64 * 8);
      int row = wx + ky;
#pragma unroll
      for (int f = 0; f < 3; ++f) {
        int col = f * 16 + (lane & 15) + kx;
        s16x8 bf = *(const s16x8*)(&S[row][col][g8]);
        acc[0][f] = __builtin_amdgcn_mfma_f32_16x16x32_bf16(a0, bf, acc[0][f], 0, 0, 0);
        acc[1][f] = __builtin_amdgcn_mfma_f32_16x16x32_bf16(a1, bf, acc[1][f], 0, 0, 0);
      }
    }
  }
  int hout = h0 + wx;
#pragma unroll
  for (int m = 0; m < 2; ++m) {
    int co0 = coB * 64 + wy * 32 + m * 16;
#pragma unroll
    for (int r = 0; r < 4; ++r) {
      int co = co0 + (lane >> 4) * 4 + r;
      float bv = bias[co];
      float s = AFFINE ? gbsum[b * NC + co] : 0.f;
#pragma unroll
      for (int f = 0; f < 3; ++f) {
        int w = f * 16 + (lane & 15);
        size_t o = (((size_t)b * NC + co) * NH + hout) * NW + w;
        float v = acc[m][f][r] + bv;
        if (AFFINE) v = v * (1.f + s) + s;
        if (RESID) v += resid[o];
        out[o] = v;
      }
    }
  }
}

// ---------------- out conv 3x3 via MFMA, CI=16 (zero-padded K to 32), in-place resid ----
__global__ __launch_bounds__(256) void out_conv_mfma_kernel(const short* __restrict__ aot,
                                                            const short* __restrict__ wbuf,
                                                            const float* __restrict__ bias,
                                                            float* __restrict__ out) {
  __shared__ short S[4][50][40];
  int bs = blockIdx.x;
  int b = bs / 24;
  int strip = bs - b * 24;
  int coB = blockIdx.y;
  int h0 = strip * 2;
  int tid = threadIdx.x;
  int lane = tid & 63, wave = tid >> 6;
  int wy = wave >> 1, wx = wave & 1;
  int g8 = (lane >> 4) * 8;

  f32x4 acc[2][3];
#pragma unroll
  for (int m = 0; m < 2; ++m)
#pragma unroll
    for (int f = 0; f < 3; ++f) acc[m][f] = (f32x4){0.f, 0.f, 0.f, 0.f};

  const size_t base = ((size_t)b * PH + h0) * PWS * 16;
  // stage: granules 0-1 real (16 ch), 2-3 zero
  for (int i = tid; i < 800; i += 256) {
    int ci8 = i & 3;
    int rc  = i >> 2;
    int col = rc % 50, r = rc / 50;
    s16x8 v = (s16x8){0, 0, 0, 0, 0, 0, 0, 0};
    if (ci8 < 2)
      v = *(const s16x8*)(aot + base + ((size_t)r * PWS + col) * 16 + ci8 * 8);
    *(s16x8*)(&S[r][col][ci8 * 8]) = v;
  }
  __syncthreads();
#pragma unroll
  for (int t = 0; t < 9; ++t) {
    int ky = t / 3, kx = t - ky * 3;
    const short* wp = wbuf + (((size_t)t * 12 + (coB * 4 + wy * 2)) * 64 + lane) * 8;
    s16x8 a0 = *(const s16x8*)wp;
    s16x8 a1 = *(const s16x8*)(wp + 64 * 8);
    int row = wx + ky;
#pragma unroll
    for (int f = 0; f < 3; ++f) {
      int col = f * 16 + (lane & 15) + kx;
      s16x8 bf = *(const s16x8*)(&S[row][col][g8]);
      acc[0][f] = __builtin_amdgcn_mfma_f32_16x16x32_bf16(a0, bf, acc[0][f], 0, 0, 0);
      acc[1][f] = __builtin_amdgcn_mfma_f32_16x16x32_bf16(a1, bf, acc[1][f], 0, 0, 0);
    }
  }
  int hout = h0 + wx;
#pragma unroll
  for (int m = 0; m < 2; ++m) {
    int co0 = coB * 64 + wy * 32 + m * 16;
#pragma unroll
    for (int r = 0; r < 4; ++r) {
      int co = co0 + (lane >> 4) * 4 + r;
      float bv = bias[co];
#pragma unroll
      for (int f = 0; f < 3; ++f) {
        int w = f * 16 + (lane & 15);
        size_t o = (((size_t)b * NC + co) * NH + hout) * NW + w;
        out[o] = acc[m][f][r] + bv + out[o];
      }
    }
  }
}

// ---------------- split-K 1x1-conv partials: part[ch][b][o][p] ----------------
template <int NOUT>
__global__ __launch_bounds__(256) void prep_partial_kernel(const float* __restrict__ X,
                                                           const float* __restrict__ W,
                                                           float* __restrict__ part) {
  __shared__ float wl[NOUT][64];
  int pt = blockIdx.x, ch = blockIdx.y, b = blockIdx.z;
  for (int i = threadIdx.x; i < NOUT * 64; i += 256) {
    int o = i >> 6, c = i & 63;
    wl[o][c] = W[o * NC + ch * 64 + c];
  }
  __syncthreads();
  int p = pt * 256 + threadIdx.x;
  const float* ip = X + ((size_t)b * NC + ch * 64) * NP + p;
  float acc[NOUT];
#pragma unroll
  for (int o = 0; o < NOUT; ++o) acc[o] = 0.f;
#pragma unroll 8
  for (int ci = 0; ci < 64; ++ci) {
    float xv = ip[(size_t)ci * NP];
#pragma unroll
    for (int o = 0; o < NOUT; ++o) acc[o] += xv * wl[o][ci];
  }
  float* op = part + ((size_t)(ch * NB + b) * NOUT) * NP + p;
#pragma unroll
  for (int o = 0; o < NOUT; ++o) op[(size_t)o * NP] = acc[o];
}

// ---------------- pack: partials -> Qb[p][32] (scaled, zero-pad), Kb[p][32], VTb[16][p]
__global__ __launch_bounds__(256) void prep_pack_kernel(const float* __restrict__ pq,
                                                        const float* __restrict__ pkv,
                                                        short* __restrict__ Qb,
                                                        short* __restrict__ Kb,
                                                        short* __restrict__ VTb) {
  __shared__ short QL[16][264], KL[16][264];
  int pt = blockIdx.x, b = blockIdx.y;
  int tp = threadIdx.x;
  int p  = pt * 256 + tp;
  const float SC = 0.36067376022224085f;  // 0.25 * log2(e)
#pragma unroll
  for (int o = 0; o < 16; ++o) {
    float s = pq[((size_t)(0 * NB + b) * 16 + o) * NP + p] +
              pq[((size_t)(1 * NB + b) * 16 + o) * NP + p] +
              pq[((size_t)(2 * NB + b) * 16 + o) * NP + p];
    QL[o][tp] = f2bf(s * SC);
  }
#pragma unroll
  for (int o = 0; o < 32; ++o) {
    float s = pkv[((size_t)(0 * NB + b) * 32 + o) * NP + p] +
              pkv[((size_t)(1 * NB + b) * 32 + o) * NP + p] +
              pkv[((size_t)(2 * NB + b) * 32 + o) * NP + p];
    if (o < 16) KL[o][tp] = f2bf(s);
    else VTb[((size_t)b * 16 + (o - 16)) * NP + p] = f2bf(s);
  }
  __syncthreads();
  short* qp = Qb + ((size_t)b * NP + p) * 32;
  short* kp = Kb + ((size_t)b * NP + p) * 32;
#pragma unroll
  for (int o4 = 0; o4 < 4; ++o4) {
    s16x4 vq = {QL[o4 * 4 + 0][tp], QL[o4 * 4 + 1][tp], QL[o4 * 4 + 2][tp], QL[o4 * 4 + 3][tp]};
    s16x4 vk = {KL[o4 * 4 + 0][tp], KL[o4 * 4 + 1][tp], KL[o4 * 4 + 2][tp], KL[o4 * 4 + 3][tp]};
    *(s16x4*)(qp + o4 * 4) = vq;
    *(s16x4*)(kp + o4 * 4) = vk;
    *(s16x4*)(qp + 16 + o4 * 4) = (s16x4){0, 0, 0, 0};
    *(s16x4*)(kp + 16 + o4 * 4) = (s16x4){0, 0, 0, 0};
  }
}

// ---------------- MFMA flash attention; writes padded-transposed bf16 aobuf_t ----------
__global__ __launch_bounds__(256) void attn_mfma_kernel(const short* __restrict__ Qb,
                                                        const short* __restrict__ Kb,
                                                        const short* __restrict__ VTb,
                                                        short* __restrict__ aot) {
  int b    = blockIdx.y;
  int lane = threadIdx.x & 63;
  int wave = threadIdx.x >> 6;
  int q0   = (blockIdx.x * 4 + wave) * 16;
  int g    = lane >> 4;
  int ql   = lane & 15;

  s16x8 qfrag = *(const s16x8*)(Qb + ((size_t)b * NP + q0 + ql) * 32 + g * 8);

  int r0 = 8 * (ql >> 2) + (ql & 3);
  const short* Kbase = Kb + (size_t)b * NP * 32 + g * 8;
  const short* Vbase = VTb + ((size_t)b * 16 + ql) * NP;

  f32x4 acc = {0.f, 0.f, 0.f, 0.f};
  float m = -1e30f, l = 0.f;

  s16x8 kf0 = *(const s16x8*)(Kbase + (size_t)r0 * 32);
  s16x8 kf1 = *(const s16x8*)(Kbase + (size_t)(r0 + 4) * 32);
  s16x8 vf  = *(const s16x8*)(Vbase + g * 8);

  for (int step = 0; step < 72; ++step) {
    int k0n = (step < 71) ? (step + 1) * 32 : 0;
    s16x8 nk0 = *(const s16x8*)(Kbase + (size_t)(k0n + r0) * 32);
    s16x8 nk1 = *(const s16x8*)(Kbase + (size_t)(k0n + r0 + 4) * 32);
    s16x8 nv  = *(const s16x8*)(Vbase + k0n + g * 8);

    f32x4 z = {0.f, 0.f, 0.f, 0.f};
    f32x4 s0 = __builtin_amdgcn_mfma_f32_16x16x32_bf16(kf0, qfrag, z, 0, 0, 0);
    f32x4 s1 = __builtin_amdgcn_mfma_f32_16x16x32_bf16(kf1, qfrag, z, 0, 0, 0);

    float tm = fmaxf(fmaxf(fmaxf(s0[0], s0[1]), fmaxf(s0[2], s0[3])),
                     fmaxf(fmaxf(s1[0], s1[1]), fmaxf(s1[2], s1[3])));
    tm = fmaxf(tm, __shfl_xor(tm, 16, 64));
    tm = fmaxf(tm, __shfl_xor(tm, 32, 64));
    float mn = fmaxf(m, tm);
    float corr = exp2f(m - mn);
    m = mn;
    float p0 = exp2f(s0[0] - m), p1 = exp2f(s0[1] - m);
    float p2 = exp2f(s0[2] - m), p3 = exp2f(s0[3] - m);
    float p4 = exp2f(s1[0] - m), p5 = exp2f(s1[1] - m);
    float p6 = exp2f(s1[2] - m), p7 = exp2f(s1[3] - m);
    l = l * corr + ((p0 + p1) + (p2 + p3)) + ((p4 + p5) + (p6 + p7));
    acc[0] *= corr; acc[1] *= corr; acc[2] *= corr; acc[3] *= corr;

    s16x8 pf;
    pf[0] = f2bf(p0); pf[1] = f2bf(p1); pf[2] = f2bf(p2); pf[3] = f2bf(p3);
    pf[4] = f2bf(p4); pf[5] = f2bf(p5); pf[6] = f2bf(p6); pf[7] = f2bf(p7);
    acc = __builtin_amdgcn_mfma_f32_16x16x32_bf16(vf, pf, acc, 0, 0, 0);

    kf0 = nk0; kf1 = nk1; vf = nv;
  }
  l += __shfl_xor(l, 16, 64);
  l += __shfl_xor(l, 32, 64);
  float inv = 1.f / l;
  // lane holds out[q][d=4g..4g+3] -> aobuf_t[b][h+1][w+1][d], dense 512B per wave
  int q = q0 + ql;
  int h = q / NW, w = q - h * NW;
  s16x4 o;
  o.x = f2bf(acc[0] * inv);
  o.y = f2bf(acc[1] * inv);
  o.z = f2bf(acc[2] * inv);
  o.w = f2bf(acc[3] * inv);
  *(s16x4*)(aot + (((size_t)b * PH + h + 1) * PWS + w + 1) * 16 + g * 4) = o;
}

// ---------------- launch ----------------
extern "C" void kernel_launch(void* const* d_in, const int* in_sizes, int n_in,
                              void* d_out, int out_size, void* d_ws, size_t ws_size,
                              hipStream_t stream) {
  const float* x      = (const float*)d_in[0];
  const float* xe     = (const float*)d_in[1];
  const float* temb   = (const float*)d_in[2];
  const float* gn1w   = (const float*)d_in[3];
  const float* gn1b   = (const float*)d_in[4];
  const float* conv1w = (const float*)d_in[5];
  const float* conv1b = (const float*)d_in[6];
  const float* affw   = (const float*)d_in[7];
  const float* affb   = (const float*)d_in[8];
  const float* gn2w   = (const float*)d_in[9];
  const float* gn2b   = (const float*)d_in[10];
  const float* conv2w = (const float*)d_in[11];
  const float* conv2b = (const float*)d_in[12];
  const float* qw     = (const float*)d_in[13];
  const float* kvw    = (const float*)d_in[14];
  const float* outw   = (const float*)d_in[15];
  const float* outb   = (const float*)d_in[16];
  float* out = (float*)d_out;
  float* ws  = (float*)d_ws;

  // ws layout (f32 region first, then bf16 region)
  float* gbsum  = ws;                                    // 1,536
  float* stats  = gbsum + NB * NC;                       // 512
  float* partQ  = stats + 512;                           // 3*8*16*NP = 884,736
  float* partKV = partQ + (size_t)3 * NB * 16 * NP;      // 3*8*32*NP = 1,769,472
  short* wbuf1  = (short*)(partKV + (size_t)3 * NB * 32 * NP);  // 331,776 bf16
  short* wbuf2  = wbuf1 + (size_t)6 * 9 * 12 * 64 * 8;          // 331,776 bf16
  short* wbufo  = wbuf2 + (size_t)6 * 9 * 12 * 64 * 8;          // 55,296 bf16
  short* actt   = wbufo + (size_t)9 * 12 * 64 * 8;              // 3,993,600 bf16
  short* Qb     = actt + ACT_T_ELEMS;                           // 589,824 bf16
  short* Kb     = Qb + (size_t)NB * NP * 32;                    // 589,824 bf16
  short* VTb    = Kb + (size_t)NB * NP * 32;                    // 294,912 bf16
  short* aot    = VTb + (size_t)NB * 16 * NP;                   // 332,800 bf16

  // prep
  wprep_kernel<<<1296, 256, 0, stream>>>(conv1w, wbuf1);
  wprep_kernel<<<1296, 256, 0, stream>>>(conv2w, wbuf2);
  wprep_o_kernel<<<216, 256, 0, stream>>>(outw, wbufo);
  affine_kernel<<<6, 256, 0, stream>>>(temb, affw, affb, gbsum);
  halo_zero_kernel<<<dim3(38, NB), 256, 0, stream>>>(actt);
  halo_zero16_kernel<<<NB, 256, 0, stream>>>(aot);
  // kv prep is independent of the resnet chain — run it early
  prep_partial_kernel<32><<<dim3(9, 3, NB), 256, 0, stream>>>(xe, kvw, partKV);

  // ----- ResnetBlock -----
  gn_stats_kernel<<<NB * NGROUPS, 256, 0, stream>>>(x, stats);
  gn_apply_t_kernel<<<NB * NH, 256, 0, stream>>>(x, stats, gn1w, gn1b, actt);
  conv_mfma_kernel<true, false><<<dim3(NB * 24, 3), 256, 0, stream>>>(
      actt, wbuf1, conv1b, gbsum, nullptr, out);
  gn_stats_kernel<<<NB * NGROUPS, 256, 0, stream>>>(out, stats);
  gn_apply_t_kernel<<<NB * NH, 256, 0, stream>>>(out, stats, gn2w, gn2b, actt);
  conv_mfma_kernel<false, true><<<dim3(NB * 24, 3), 256, 0, stream>>>(
      actt, wbuf2, conv2b, nullptr, x, out);

  // ----- CrossAttention -----
  prep_partial_kernel<16><<<dim3(9, 3, NB), 256, 0, stream>>>(out, qw, partQ);
  prep_pack_kernel<<<dim3(9, NB), 256, 0, stream>>>(partQ, partKV, Qb, Kb, VTb);
  attn_mfma_kernel<<<dim3(36, NB), 256, 0, stream>>>(Qb, Kb, VTb, aot);
  out_conv_mfma_kernel<<<dim3(NB * 24, 3), 256, 0, stream>>>(aot, wbufo, outb, out);
}

// Round 7
// 300.782 us; speedup vs baseline: 3.4847x; 1.0248x over previous
//
#include <hip/hip_runtime.h>
#include <hip/hip_bf16.h>

#define NB 8
#define NC 192
#define NH 48
#define NW 48
#define NP 2304        // 48*48
#define NGROUPS 32
#define CPG 6          // NC/NGROUPS
#define NEMB 192
#define NCQ 16

// padded-transposed activation: [B][50 h'][52 w' stride (50 used)][192 c] bf16
#define PH 50
#define PWS 52
#define ACT_T_ELEMS ((size_t)NB * PH * PWS * NC)   // 3,993,600 bf16
#define AOT_ELEMS   ((size_t)NB * PH * PWS * 16)   // 332,800 bf16

typedef __attribute__((ext_vector_type(4))) short s16x4;
typedef __attribute__((ext_vector_type(8))) short s16x8;
typedef __attribute__((ext_vector_type(4))) float f32x4;

static __device__ inline short f2bf(float v) {
  __hip_bfloat16 h = __float2bfloat16(v);
  return *(short*)&h;
}

// ---------------- MFMA weight prep (conv1/conv2): wbuf[kc6][t9][cf12][lane64][j8] bf16
__global__ __launch_bounds__(256) void wprep_kernel(const float* __restrict__ w,
                                                    short* __restrict__ wbuf) {
  int i = blockIdx.x * 256 + threadIdx.x;
  if (i >= 6 * 9 * 12 * 64 * 8) return;
  int j  = i & 7;
  int l  = (i >> 3) & 63;
  int cf = (i >> 9) % 12;
  int tk = (i >> 9) / 12;      // kc*9 + t
  int t  = tk % 9;
  int kc = tk / 9;
  int co = cf * 16 + (l & 15);
  int ci = kc * 32 + (l >> 4) * 8 + j;
  wbuf[i] = f2bf(w[((size_t)co * NC + ci) * 9 + t]);
}

// ---------------- MFMA weight prep (out conv, CI=16 padded to 32): wbuf_o[t9][cf12][l64][j8]
__global__ __launch_bounds__(256) void wprep_o_kernel(const float* __restrict__ w,
                                                      short* __restrict__ wbuf) {
  int i = blockIdx.x * 256 + threadIdx.x;
  if (i >= 9 * 12 * 64 * 8) return;
  int j  = i & 7;
  int l  = (i >> 3) & 63;
  int cf = (i >> 9) % 12;
  int t  = (i >> 9) / 12;
  int co = cf * 16 + (l & 15);
  int ci = (l >> 4) * 8 + j;   // 0..31; real for ci<16
  wbuf[i] = (ci < 16) ? f2bf(w[((size_t)co * 16 + ci) * 9 + t]) : (short)0;
}

// ---------------- FeatureWiseAffine GEMV ----------------
__global__ __launch_bounds__(256) void affine_kernel(const float* __restrict__ emb,
                                                     const float* __restrict__ aw,
                                                     const float* __restrict__ ab,
                                                     float* __restrict__ gbsum) {
  int i = blockIdx.x * 256 + threadIdx.x;
  if (i >= NB * NC) return;
  int b = i / NC;
  int c = i - b * NC;
  const float* e  = emb + b * NEMB;
  const float* w0 = aw + c * NEMB;
  const float* w1 = aw + (c + NC) * NEMB;
  float s = 0.f;
  for (int j = 0; j < NEMB; ++j) s += e[j] * (w0[j] + w1[j]);
  gbsum[i] = 0.5f * (s + ab[c] + ab[c + NC]);
}

// ---------------- halo zero for actt ----------------
__global__ __launch_bounds__(256) void halo_zero_kernel(short* __restrict__ actt) {
  int b = blockIdx.y;
  int i = blockIdx.x * 256 + threadIdx.x;   // short4 granules; 9600 per b
  if (i >= 9600) return;
  int c4 = i % 48;
  int r  = i / 48;                          // 0..199
  size_t off;
  if (r < 52)       off = ((size_t)0 * PWS + r) * NC;
  else if (r < 104) off = ((size_t)49 * PWS + (r - 52)) * NC;
  else if (r < 152) off = ((size_t)(r - 104 + 1) * PWS + 0) * NC;
  else              off = ((size_t)(r - 152 + 1) * PWS + 49) * NC;
  *(s16x4*)(&actt[(size_t)b * PH * PWS * NC + off + c4 * 4]) = (s16x4){0, 0, 0, 0};
}

// ---------------- halo zero for aobuf_t (16 ch) ----------------
__global__ __launch_bounds__(256) void halo_zero16_kernel(short* __restrict__ aot) {
  int b = blockIdx.x;
  for (int i = threadIdx.x; i < 784; i += 256) {  // 196 positions x 4 granules
    int c4  = i & 3;
    int pos = i >> 2;
    int r, col;
    if (pos < 50)       { r = 0;  col = pos; }
    else if (pos < 100) { r = 49; col = pos - 50; }
    else if (pos < 148) { r = pos - 100 + 1; col = 0; }
    else                { r = pos - 148 + 1; col = 49; }
    *(s16x4*)(&aot[(((size_t)b * PH + r) * PWS + col) * 16 + c4 * 4]) = (s16x4){0, 0, 0, 0};
  }
}

// ---------------- GroupNorm stats ----------------
__global__ __launch_bounds__(256) void gn_stats_kernel(const float* __restrict__ in,
                                                       float* __restrict__ stats) {
  int bg = blockIdx.x;
  const float4* p = (const float4*)(in + (size_t)bg * (CPG * NP));
  float s = 0.f, s2 = 0.f;
  for (int i = threadIdx.x; i < CPG * NP / 4; i += 256) {
    float4 v = p[i];
    s  += v.x + v.y + v.z + v.w;
    s2 += v.x * v.x + v.y * v.y + v.z * v.z + v.w * v.w;
  }
#pragma unroll
  for (int off = 32; off > 0; off >>= 1) {
    s  += __shfl_down(s, off);
    s2 += __shfl_down(s2, off);
  }
  __shared__ float red[8];
  int wave = threadIdx.x >> 6;
  if ((threadIdx.x & 63) == 0) { red[wave * 2] = s; red[wave * 2 + 1] = s2; }
  __syncthreads();
  if (threadIdx.x == 0) {
    float S  = red[0] + red[2] + red[4] + red[6];
    float S2 = red[1] + red[3] + red[5] + red[7];
    const float invN = 1.f / (float)(CPG * NP);
    float mean = S * invN;
    float var  = S2 * invN - mean * mean;
    stats[bg * 2]     = mean;
    stats[bg * 2 + 1] = rsqrtf(var + 1e-5f);
  }
}

// ---------------- GN apply + swish -> padded TRANSPOSED bf16 act_t ----------------
__global__ __launch_bounds__(256) void gn_apply_t_kernel(const float* __restrict__ in,
                                                         const float* __restrict__ stats,
                                                         const float* __restrict__ gw,
                                                         const float* __restrict__ gb,
                                                         short* __restrict__ actt) {
  __shared__ float tile[48 * 193];
  int bh = blockIdx.x;
  int b = bh / NH;
  int h = bh - b * NH;
  int tid = threadIdx.x;
  for (int i = tid; i < 2304; i += 256) {
    int c = i / 12;
    int w = (i % 12) * 4;
    float4 v = *(const float4*)(in + (((size_t)b * NC + c) * NH + h) * NW + w);
    float mean = stats[(b * NGROUPS + c / CPG) * 2];
    float rstd = stats[(b * NGROUPS + c / CPG) * 2 + 1];
    float sc = rstd * gw[c];
    float sh = gb[c] - mean * sc;
    float y;
    y = v.x * sc + sh; tile[(w + 0) * 193 + c] = y / (1.f + __expf(-y));
    y = v.y * sc + sh; tile[(w + 1) * 193 + c] = y / (1.f + __expf(-y));
    y = v.z * sc + sh; tile[(w + 2) * 193 + c] = y / (1.f + __expf(-y));
    y = v.w * sc + sh; tile[(w + 3) * 193 + c] = y / (1.f + __expf(-y));
  }
  __syncthreads();
  short* dst = actt + (((size_t)b * PH + h + 1) * PWS + 1) * NC;
  for (int i = tid; i < 2304; i += 256) {
    int w  = i / 48;
    int c4 = (i - w * 48) * 4;
    s16x4 o;
    o.x = f2bf(tile[w * 193 + c4 + 0]);
    o.y = f2bf(tile[w * 193 + c4 + 1]);
    o.z = f2bf(tile[w * 193 + c4 + 2]);
    o.w = f2bf(tile[w * 193 + c4 + 3]);
    *(s16x4*)(dst + (size_t)w * NC + c4) = o;
  }
}

// ---------------- conv3x3 via MFMA (tap-decomposed implicit GEMM), CI=192 ----------------
template <bool AFFINE, bool RESID>
__global__ __launch_bounds__(256) void conv_mfma_kernel(const short* __restrict__ actt,
                                                        const short* __restrict__ wbuf,
                                                        const float* __restrict__ bias,
                                                        const float* __restrict__ gbsum,
                                                        const float* __restrict__ resid,
                                                        float* __restrict__ out) {
  __shared__ short S[4][50][40];
  int bs = blockIdx.x;
  int b = bs / 24;
  int strip = bs - b * 24;
  int coB = blockIdx.y;
  int h0 = strip * 2;
  int tid = threadIdx.x;
  int lane = tid & 63, wave = tid >> 6;
  int wy = wave >> 1, wx = wave & 1;
  int g8 = (lane >> 4) * 8;

  f32x4 acc[2][3];
#pragma unroll
  for (int m = 0; m < 2; ++m)
#pragma unroll
    for (int f = 0; f < 3; ++f) acc[m][f] = (f32x4){0.f, 0.f, 0.f, 0.f};

  const size_t actbase = ((size_t)b * PH + h0) * PWS * NC;

  for (int kc = 0; kc < 6; ++kc) {
    __syncthreads();
    for (int i = tid; i < 800; i += 256) {
      int ci8 = i & 3;
      int rc  = i >> 2;
      int col = rc % 50, r = rc / 50;
      const s16x8* src = (const s16x8*)(actt + actbase + ((size_t)r * PWS + col) * NC +
                                        kc * 32 + ci8 * 8);
      *(s16x8*)(&S[r][col][ci8 * 8]) = *src;
    }
    __syncthreads();
#pragma unroll
    for (int t = 0; t < 9; ++t) {
      int ky = t / 3, kx = t - ky * 3;
      const short* wp = wbuf + ((((size_t)kc * 9 + t) * 12 + (coB * 4 + wy * 2)) * 64 + lane) * 8;
      s16x8 a0 = *(const s16x8*)wp;
      s16x8 a1 = *(const s16x8*)(wp + 64 * 8);
      int row = wx + ky;
#pragma unroll
      for (int f = 0; f < 3; ++f) {
        int col = f * 16 + (lane & 15) + kx;
        s16x8 bf = *(const s16x8*)(&S[row][col][g8]);
        acc[0][f] = __builtin_amdgcn_mfma_f32_16x16x32_bf16(a0, bf, acc[0][f], 0, 0, 0);
        acc[1][f] = __builtin_amdgcn_mfma_f32_16x16x32_bf16(a1, bf, acc[1][f], 0, 0, 0);
      }
    }
  }
  int hout = h0 + wx;
#pragma unroll
  for (int m = 0; m < 2; ++m) {
    int co0 = coB * 64 + wy * 32 + m * 16;
#pragma unroll
    for (int r = 0; r < 4; ++r) {
      int co = co0 + (lane >> 4) * 4 + r;
      float bv = bias[co];
      float s = AFFINE ? gbsum[b * NC + co] : 0.f;
#pragma unroll
      for (int f = 0; f < 3; ++f) {
        int w = f * 16 + (lane & 15);
        size_t o = (((size_t)b * NC + co) * NH + hout) * NW + w;
        float v = acc[m][f][r] + bv;
        if (AFFINE) v = v * (1.f + s) + s;
        if (RESID) v += resid[o];
        out[o] = v;
      }
    }
  }
}

// ---------------- out conv 3x3 via MFMA, CI=16 (zero-padded K to 32), in-place resid ----
__global__ __launch_bounds__(256) void out_conv_mfma_kernel(const short* __restrict__ aot,
                                                            const short* __restrict__ wbuf,
                                                            const float* __restrict__ bias,
                                                            float* __restrict__ out) {
  __shared__ short S[4][50][40];
  int bs = blockIdx.x;
  int b = bs / 24;
  int strip = bs - b * 24;
  int coB = blockIdx.y;
  int h0 = strip * 2;
  int tid = threadIdx.x;
  int lane = tid & 63, wave = tid >> 6;
  int wy = wave >> 1, wx = wave & 1;
  int g8 = (lane >> 4) * 8;

  f32x4 acc[2][3];
#pragma unroll
  for (int m = 0; m < 2; ++m)
#pragma unroll
    for (int f = 0; f < 3; ++f) acc[m][f] = (f32x4){0.f, 0.f, 0.f, 0.f};

  const size_t base = ((size_t)b * PH + h0) * PWS * 16;
  for (int i = tid; i < 800; i += 256) {
    int ci8 = i & 3;
    int rc  = i >> 2;
    int col = rc % 50, r = rc / 50;
    s16x8 v = (s16x8){0, 0, 0, 0, 0, 0, 0, 0};
    if (ci8 < 2)
      v = *(const s16x8*)(aot + base + ((size_t)r * PWS + col) * 16 + ci8 * 8);
    *(s16x8*)(&S[r][col][ci8 * 8]) = v;
  }
  __syncthreads();
#pragma unroll
  for (int t = 0; t < 9; ++t) {
    int ky = t / 3, kx = t - ky * 3;
    const short* wp = wbuf + (((size_t)t * 12 + (coB * 4 + wy * 2)) * 64 + lane) * 8;
    s16x8 a0 = *(const s16x8*)wp;
    s16x8 a1 = *(const s16x8*)(wp + 64 * 8);
    int row = wx + ky;
#pragma unroll
    for (int f = 0; f < 3; ++f) {
      int col = f * 16 + (lane & 15) + kx;
      s16x8 bf = *(const s16x8*)(&S[row][col][g8]);
      acc[0][f] = __builtin_amdgcn_mfma_f32_16x16x32_bf16(a0, bf, acc[0][f], 0, 0, 0);
      acc[1][f] = __builtin_amdgcn_mfma_f32_16x16x32_bf16(a1, bf, acc[1][f], 0, 0, 0);
    }
  }
  int hout = h0 + wx;
#pragma unroll
  for (int m = 0; m < 2; ++m) {
    int co0 = coB * 64 + wy * 32 + m * 16;
#pragma unroll
    for (int r = 0; r < 4; ++r) {
      int co = co0 + (lane >> 4) * 4 + r;
      float bv = bias[co];
#pragma unroll
      for (int f = 0; f < 3; ++f) {
        int w = f * 16 + (lane & 15);
        size_t o = (((size_t)b * NC + co) * NH + hout) * NW + w;
        out[o] = acc[m][f][r] + bv + out[o];
      }
    }
  }
}

// ---------------- split-K 1x1-conv partials: part[ch][b][o][p] ----------------
template <int NOUT>
__global__ __launch_bounds__(256) void prep_partial_kernel(const float* __restrict__ X,
                                                           const float* __restrict__ W,
                                                           float* __restrict__ part) {
  __shared__ float wl[NOUT][64];
  int pt = blockIdx.x, ch = blockIdx.y, b = blockIdx.z;
  for (int i = threadIdx.x; i < NOUT * 64; i += 256) {
    int o = i >> 6, c = i & 63;
    wl[o][c] = W[o * NC + ch * 64 + c];
  }
  __syncthreads();
  int p = pt * 256 + threadIdx.x;
  const float* ip = X + ((size_t)b * NC + ch * 64) * NP + p;
  float acc[NOUT];
#pragma unroll
  for (int o = 0; o < NOUT; ++o) acc[o] = 0.f;
#pragma unroll 8
  for (int ci = 0; ci < 64; ++ci) {
    float xv = ip[(size_t)ci * NP];
#pragma unroll
    for (int o = 0; o < NOUT; ++o) acc[o] += xv * wl[o][ci];
  }
  float* op = part + ((size_t)(ch * NB + b) * NOUT) * NP + p;
#pragma unroll
  for (int o = 0; o < NOUT; ++o) op[(size_t)o * NP] = acc[o];
}

// ---------------- pack: partials -> Qb[p][32] (scaled, zero-pad), Kb[p][32], VTb[16][p]
__global__ __launch_bounds__(256) void prep_pack_kernel(const float* __restrict__ pq,
                                                        const float* __restrict__ pkv,
                                                        short* __restrict__ Qb,
                                                        short* __restrict__ Kb,
                                                        short* __restrict__ VTb) {
  __shared__ short QL[16][264], KL[16][264];
  int pt = blockIdx.x, b = blockIdx.y;
  int tp = threadIdx.x;
  int p  = pt * 256 + tp;
  const float SC = 0.36067376022224085f;  // 0.25 * log2(e)
#pragma unroll
  for (int o = 0; o < 16; ++o) {
    float s = pq[((size_t)(0 * NB + b) * 16 + o) * NP + p] +
              pq[((size_t)(1 * NB + b) * 16 + o) * NP + p] +
              pq[((size_t)(2 * NB + b) * 16 + o) * NP + p];
    QL[o][tp] = f2bf(s * SC);
  }
#pragma unroll
  for (int o = 0; o < 32; ++o) {
    float s = pkv[((size_t)(0 * NB + b) * 32 + o) * NP + p] +
              pkv[((size_t)(1 * NB + b) * 32 + o) * NP + p] +
              pkv[((size_t)(2 * NB + b) * 32 + o) * NP + p];
    if (o < 16) KL[o][tp] = f2bf(s);
    else VTb[((size_t)b * 16 + (o - 16)) * NP + p] = f2bf(s);
  }
  __syncthreads();
  short* qp = Qb + ((size_t)b * NP + p) * 32;
  short* kp = Kb + ((size_t)b * NP + p) * 32;
#pragma unroll
  for (int o4 = 0; o4 < 4; ++o4) {
    s16x4 vq = {QL[o4 * 4 + 0][tp], QL[o4 * 4 + 1][tp], QL[o4 * 4 + 2][tp], QL[o4 * 4 + 3][tp]};
    s16x4 vk = {KL[o4 * 4 + 0][tp], KL[o4 * 4 + 1][tp], KL[o4 * 4 + 2][tp], KL[o4 * 4 + 3][tp]};
    *(s16x4*)(qp + o4 * 4) = vq;
    *(s16x4*)(kp + o4 * 4) = vk;
    *(s16x4*)(qp + 16 + o4 * 4) = (s16x4){0, 0, 0, 0};
    *(s16x4*)(kp + 16 + o4 * 4) = (s16x4){0, 0, 0, 0};
  }
}

// ---------------- MFMA flash attention, KS=4 key-split + defer-max ----------------
// grid (36, NB), block 1024 = 16 waves: wave = qg(4) x ks(4). Wave does 576 keys (18
// steps); partial (m,l,acc) merged in LDS by ks==0 waves. Common path has NO cross-lane
// ops: m stays per-query-uniform; rescale triggered only when __all(tm <= m+8) fails.
__global__ __launch_bounds__(1024) void attn_mfma_kernel(const short* __restrict__ Qb,
                                                         const short* __restrict__ Kb,
                                                         const short* __restrict__ VTb,
                                                         short* __restrict__ aot) {
  __shared__ float PM[4][4][64], PL[4][4][64];
  __shared__ f32x4 PA[4][4][64];
  int b    = blockIdx.y;
  int tid  = threadIdx.x;
  int lane = tid & 63;
  int w    = tid >> 6;
  int qg   = w & 3, ks = w >> 2;
  int q0   = blockIdx.x * 64 + qg * 16;
  int g    = lane >> 4;
  int ql   = lane & 15;

  s16x8 qfrag = *(const s16x8*)(Qb + ((size_t)b * NP + q0 + ql) * 32 + g * 8);

  int r0 = 8 * (ql >> 2) + (ql & 3);
  const short* Kbase = Kb + (size_t)b * NP * 32 + g * 8;
  const short* Vbase = VTb + ((size_t)b * 16 + ql) * NP;

  f32x4 acc = {0.f, 0.f, 0.f, 0.f};
  float m = -1e30f, l = 0.f;

  int kk = ks * 576;
  s16x8 kf0 = *(const s16x8*)(Kbase + (size_t)(kk + r0) * 32);
  s16x8 kf1 = *(const s16x8*)(Kbase + (size_t)(kk + r0 + 4) * 32);
  s16x8 vf  = *(const s16x8*)(Vbase + kk + g * 8);

  for (int step = 0; step < 18; ++step) {
    int kn = (step < 17) ? kk + 32 : ks * 576;   // wrap dummy prefetch on last step
    s16x8 nk0 = *(const s16x8*)(Kbase + (size_t)(kn + r0) * 32);
    s16x8 nk1 = *(const s16x8*)(Kbase + (size_t)(kn + r0 + 4) * 32);
    s16x8 nv  = *(const s16x8*)(Vbase + kn + g * 8);

    f32x4 z = {0.f, 0.f, 0.f, 0.f};
    f32x4 s0 = __builtin_amdgcn_mfma_f32_16x16x32_bf16(kf0, qfrag, z, 0, 0, 0);
    f32x4 s1 = __builtin_amdgcn_mfma_f32_16x16x32_bf16(kf1, qfrag, z, 0, 0, 0);

    float tm = fmaxf(fmaxf(fmaxf(s0[0], s0[1]), fmaxf(s0[2], s0[3])),
                     fmaxf(fmaxf(s1[0], s1[1]), fmaxf(s1[2], s1[3])));
    if (!__all(tm <= m + 8.0f)) {       // rare: full cross-group max + rescale
      tm = fmaxf(tm, __shfl_xor(tm, 16, 64));
      tm = fmaxf(tm, __shfl_xor(tm, 32, 64));
      float mn = fmaxf(m, tm);
      float corr = exp2f(m - mn);
      m = mn;
      l *= corr;
      acc[0] *= corr; acc[1] *= corr; acc[2] *= corr; acc[3] *= corr;
    }
    float p0 = exp2f(s0[0] - m), p1 = exp2f(s0[1] - m);
    float p2 = exp2f(s0[2] - m), p3 = exp2f(s0[3] - m);
    float p4 = exp2f(s1[0] - m), p5 = exp2f(s1[1] - m);
    float p6 = exp2f(s1[2] - m), p7 = exp2f(s1[3] - m);
    l += ((p0 + p1) + (p2 + p3)) + ((p4 + p5) + (p6 + p7));

    s16x8 pf;
    pf[0] = f2bf(p0); pf[1] = f2bf(p1); pf[2] = f2bf(p2); pf[3] = f2bf(p3);
    pf[4] = f2bf(p4); pf[5] = f2bf(p5); pf[6] = f2bf(p6); pf[7] = f2bf(p7);
    acc = __builtin_amdgcn_mfma_f32_16x16x32_bf16(vf, pf, acc, 0, 0, 0);

    kf0 = nk0; kf1 = nk1; vf = nv; kk = kn;
  }
  // cross-group (g) combine within the wave via per-lane write + ks-merge:
  // reduce l and acc across g AFTER the ks-merge would be wrong (m differs per ks),
  // so store per-lane partials keyed by (ks, qg, lane) and let ks==0 do everything.
  PM[ks][qg][lane] = m;
  PL[ks][qg][lane] = l;
  PA[ks][qg][lane] = acc;
  __syncthreads();
  if (ks == 0) {
    float M = PM[0][qg][lane];
#pragma unroll
    for (int k = 1; k < 4; ++k) M = fmaxf(M, PM[k][qg][lane]);
    float L = 0.f;
    f32x4 o = {0.f, 0.f, 0.f, 0.f};
#pragma unroll
    for (int k = 0; k < 4; ++k) {
      float c = exp2f(PM[k][qg][lane] - M);
      L += PL[k][qg][lane] * c;
      f32x4 a = PA[k][qg][lane];
      o[0] += a[0] * c; o[1] += a[1] * c; o[2] += a[2] * c; o[3] += a[3] * c;
    }
    // L currently holds this lane's share; l and acc still need the cross-g sum for
    // the normalizer. acc entries are per-(q, d-slice) — only l is shared across g.
    L += __shfl_xor(L, 16, 64);
    L += __shfl_xor(L, 32, 64);
    float inv = 1.f / L;
    int q = q0 + ql;
    int h = q / NW, wcol = q - h * NW;
    s16x4 ov;
    ov.x = f2bf(o[0] * inv);
    ov.y = f2bf(o[1] * inv);
    ov.z = f2bf(o[2] * inv);
    ov.w = f2bf(o[3] * inv);
    *(s16x4*)(aot + (((size_t)b * PH + h + 1) * PWS + wcol + 1) * 16 + g * 4) = ov;
  }
}

// ---------------- launch ----------------
extern "C" void kernel_launch(void* const* d_in, const int* in_sizes, int n_in,
                              void* d_out, int out_size, void* d_ws, size_t ws_size,
                              hipStream_t stream) {
  const float* x      = (const float*)d_in[0];
  const float* xe     = (const float*)d_in[1];
  const float* temb   = (const float*)d_in[2];
  const float* gn1w   = (const float*)d_in[3];
  const float* gn1b   = (const float*)d_in[4];
  const float* conv1w = (const float*)d_in[5];
  const float* conv1b = (const float*)d_in[6];
  const float* affw   = (const float*)d_in[7];
  const float* affb   = (const float*)d_in[8];
  const float* gn2w   = (const float*)d_in[9];
  const float* gn2b   = (const float*)d_in[10];
  const float* conv2w = (const float*)d_in[11];
  const float* conv2b = (const float*)d_in[12];
  const float* qw     = (const float*)d_in[13];
  const float* kvw    = (const float*)d_in[14];
  const float* outw   = (const float*)d_in[15];
  const float* outb   = (const float*)d_in[16];
  float* out = (float*)d_out;
  float* ws  = (float*)d_ws;

  // ws layout (f32 region first, then bf16 region)
  float* gbsum  = ws;                                    // 1,536
  float* stats  = gbsum + NB * NC;                       // 512
  float* partQ  = stats + 512;                           // 3*8*16*NP = 884,736
  float* partKV = partQ + (size_t)3 * NB * 16 * NP;      // 3*8*32*NP = 1,769,472
  short* wbuf1  = (short*)(partKV + (size_t)3 * NB * 32 * NP);  // 331,776 bf16
  short* wbuf2  = wbuf1 + (size_t)6 * 9 * 12 * 64 * 8;          // 331,776 bf16
  short* wbufo  = wbuf2 + (size_t)6 * 9 * 12 * 64 * 8;          // 55,296 bf16
  short* actt   = wbufo + (size_t)9 * 12 * 64 * 8;              // 3,993,600 bf16
  short* Qb     = actt + ACT_T_ELEMS;                           // 589,824 bf16
  short* Kb     = Qb + (size_t)NB * NP * 32;                    // 589,824 bf16
  short* VTb    = Kb + (size_t)NB * NP * 32;                    // 294,912 bf16
  short* aot    = VTb + (size_t)NB * 16 * NP;                   // 332,800 bf16

  // prep
  wprep_kernel<<<1296, 256, 0, stream>>>(conv1w, wbuf1);
  wprep_kernel<<<1296, 256, 0, stream>>>(conv2w, wbuf2);
  wprep_o_kernel<<<216, 256, 0, stream>>>(outw, wbufo);
  affine_kernel<<<6, 256, 0, stream>>>(temb, affw, affb, gbsum);
  halo_zero_kernel<<<dim3(38, NB), 256, 0, stream>>>(actt);
  halo_zero16_kernel<<<NB, 256, 0, stream>>>(aot);
  // kv prep is independent of the resnet chain — run it early
  prep_partial_kernel<32><<<dim3(9, 3, NB), 256, 0, stream>>>(xe, kvw, partKV);

  // ----- ResnetBlock -----
  gn_stats_kernel<<<NB * NGROUPS, 256, 0, stream>>>(x, stats);
  gn_apply_t_kernel<<<NB * NH, 256, 0, stream>>>(x, stats, gn1w, gn1b, actt);
  conv_mfma_kernel<true, false><<<dim3(NB * 24, 3), 256, 0, stream>>>(
      actt, wbuf1, conv1b, gbsum, nullptr, out);
  gn_stats_kernel<<<NB * NGROUPS, 256, 0, stream>>>(out, stats);
  gn_apply_t_kernel<<<NB * NH, 256, 0, stream>>>(out, stats, gn2w, gn2b, actt);
  conv_mfma_kernel<false, true><<<dim3(NB * 24, 3), 256, 0, stream>>>(
      actt, wbuf2, conv2b, nullptr, x, out);

  // ----- CrossAttention -----
  prep_partial_kernel<16><<<dim3(9, 3, NB), 256, 0, stream>>>(out, qw, partQ);
  prep_pack_kernel<<<dim3(9, NB), 256, 0, stream>>>(partQ, partKV, Qb, Kb, VTb);
  attn_mfma_kernel<<<dim3(36, NB), 1024, 0, stream>>>(Qb, Kb, VTb, aot);
  out_conv_mfma_kernel<<<dim3(NB * 24, 3), 256, 0, stream>>>(aot, wbufo, outb, out);
}

// Round 8
// 275.789 us; speedup vs baseline: 3.8005x; 1.0906x over previous
//
#include <hip/hip_runtime.h>
#include <hip/hip_bf16.h>

#define NB 8
#define NC 192
#define NH 48
#define NW 48
#define NP 2304        // 48*48
#define NGROUPS 32
#define CPG 6          // NC/NGROUPS
#define NEMB 192
#define NCQ 16

// padded-transposed activation: [B][50 h'][52 w' stride (50 used)][192 c] bf16
#define PH 50
#define PWS 52
#define ACT_T_ELEMS ((size_t)NB * PH * PWS * NC)   // 3,993,600 bf16
#define AOT_ELEMS   ((size_t)NB * PH * PWS * 16)   // 332,800 bf16

typedef __attribute__((ext_vector_type(4))) short s16x4;
typedef __attribute__((ext_vector_type(8))) short s16x8;
typedef __attribute__((ext_vector_type(4))) float f32x4;

static __device__ inline short f2bf(float v) {
  __hip_bfloat16 h = __float2bfloat16(v);
  return *(short*)&h;
}

// ---------------- MFMA weight prep (conv1/conv2): wbuf[kc6][t9][cf12][lane64][j8] bf16
__global__ __launch_bounds__(256) void wprep_kernel(const float* __restrict__ w,
                                                    short* __restrict__ wbuf) {
  int i = blockIdx.x * 256 + threadIdx.x;
  if (i >= 6 * 9 * 12 * 64 * 8) return;
  int j  = i & 7;
  int l  = (i >> 3) & 63;
  int cf = (i >> 9) % 12;
  int tk = (i >> 9) / 12;      // kc*9 + t
  int t  = tk % 9;
  int kc = tk / 9;
  int co = cf * 16 + (l & 15);
  int ci = kc * 32 + (l >> 4) * 8 + j;
  wbuf[i] = f2bf(w[((size_t)co * NC + ci) * 9 + t]);
}

// ---------------- MFMA weight prep (out conv, CI=16 padded to 32) ----------------
__global__ __launch_bounds__(256) void wprep_o_kernel(const float* __restrict__ w,
                                                      short* __restrict__ wbuf) {
  int i = blockIdx.x * 256 + threadIdx.x;
  if (i >= 9 * 12 * 64 * 8) return;
  int j  = i & 7;
  int l  = (i >> 3) & 63;
  int cf = (i >> 9) % 12;
  int t  = (i >> 9) / 12;
  int co = cf * 16 + (l & 15);
  int ci = (l >> 4) * 8 + j;   // 0..31; real for ci<16
  wbuf[i] = (ci < 16) ? f2bf(w[((size_t)co * 16 + ci) * 9 + t]) : (short)0;
}

// ---------------- MFMA weight prep (1x1 q/kv): aw[kc6][m NM][lane64][j8], scale folded
template <int NM>
__global__ __launch_bounds__(256) void wprep_a_kernel(const float* __restrict__ w,
                                                      short* __restrict__ aw, float scale) {
  int i = blockIdx.x * 256 + threadIdx.x;
  if (i >= 6 * NM * 64 * 8) return;
  int j = i & 7, l = (i >> 3) & 63, rest = i >> 9;
  int m = rest % NM, kc = rest / NM;
  int co = m * 16 + (l & 15);
  int ci = kc * 32 + (l >> 4) * 8 + j;
  aw[i] = f2bf(w[(size_t)co * NC + ci] * scale);
}

// ---------------- FeatureWiseAffine GEMV ----------------
__global__ __launch_bounds__(256) void affine_kernel(const float* __restrict__ emb,
                                                     const float* __restrict__ aw,
                                                     const float* __restrict__ ab,
                                                     float* __restrict__ gbsum) {
  int i = blockIdx.x * 256 + threadIdx.x;
  if (i >= NB * NC) return;
  int b = i / NC;
  int c = i - b * NC;
  const float* e  = emb + b * NEMB;
  const float* w0 = aw + c * NEMB;
  const float* w1 = aw + (c + NC) * NEMB;
  float s = 0.f;
  for (int j = 0; j < NEMB; ++j) s += e[j] * (w0[j] + w1[j]);
  gbsum[i] = 0.5f * (s + ab[c] + ab[c + NC]);
}

// ---------------- halo zero for actt ----------------
__global__ __launch_bounds__(256) void halo_zero_kernel(short* __restrict__ actt) {
  int b = blockIdx.y;
  int i = blockIdx.x * 256 + threadIdx.x;   // short4 granules; 9600 per b
  if (i >= 9600) return;
  int c4 = i % 48;
  int r  = i / 48;                          // 0..199
  size_t off;
  if (r < 52)       off = ((size_t)0 * PWS + r) * NC;
  else if (r < 104) off = ((size_t)49 * PWS + (r - 52)) * NC;
  else if (r < 152) off = ((size_t)(r - 104 + 1) * PWS + 0) * NC;
  else              off = ((size_t)(r - 152 + 1) * PWS + 49) * NC;
  *(s16x4*)(&actt[(size_t)b * PH * PWS * NC + off + c4 * 4]) = (s16x4){0, 0, 0, 0};
}

// ---------------- halo zero for aobuf_t (16 ch) ----------------
__global__ __launch_bounds__(256) void halo_zero16_kernel(short* __restrict__ aot) {
  int b = blockIdx.x;
  for (int i = threadIdx.x; i < 784; i += 256) {
    int c4  = i & 3;
    int pos = i >> 2;
    int r, col;
    if (pos < 50)       { r = 0;  col = pos; }
    else if (pos < 100) { r = 49; col = pos - 50; }
    else if (pos < 148) { r = pos - 100 + 1; col = 0; }
    else                { r = pos - 148 + 1; col = 49; }
    *(s16x4*)(&aot[(((size_t)b * PH + r) * PWS + col) * 16 + c4 * 4]) = (s16x4){0, 0, 0, 0};
  }
}

// ---------------- GroupNorm stats, split grid: partial sums ----------------
__global__ __launch_bounds__(192) void gn_stats_part_kernel(const float* __restrict__ in,
                                                            float* __restrict__ part) {
  int bg = blockIdx.x, seg = blockIdx.y;  // 256 groups x 6 segments of 2304 floats
  const float4* p = (const float4*)(in + (size_t)bg * (CPG * NP) + seg * 2304);
  float s = 0.f, s2 = 0.f;
  for (int i = threadIdx.x; i < 576; i += 192) {
    float4 v = p[i];
    s  += v.x + v.y + v.z + v.w;
    s2 += v.x * v.x + v.y * v.y + v.z * v.z + v.w * v.w;
  }
#pragma unroll
  for (int off = 32; off > 0; off >>= 1) {
    s  += __shfl_down(s, off);
    s2 += __shfl_down(s2, off);
  }
  __shared__ float red[6];
  int wave = threadIdx.x >> 6;
  if ((threadIdx.x & 63) == 0) { red[wave * 2] = s; red[wave * 2 + 1] = s2; }
  __syncthreads();
  if (threadIdx.x == 0) {
    part[(bg * 6 + seg) * 2]     = red[0] + red[2] + red[4];
    part[(bg * 6 + seg) * 2 + 1] = red[1] + red[3] + red[5];
  }
}

__global__ __launch_bounds__(256) void gn_stats_reduce_kernel(const float* __restrict__ part,
                                                              float* __restrict__ stats) {
  int bg = threadIdx.x;  // 256
  float S = 0.f, S2 = 0.f;
#pragma unroll
  for (int k = 0; k < 6; ++k) {
    S  += part[(bg * 6 + k) * 2];
    S2 += part[(bg * 6 + k) * 2 + 1];
  }
  const float invN = 1.f / (float)(CPG * NP);
  float mean = S * invN;
  float var  = S2 * invN - mean * mean;
  stats[bg * 2]     = mean;
  stats[bg * 2 + 1] = rsqrtf(var + 1e-5f);
}

// ---------------- GN apply + swish -> padded TRANSPOSED bf16 act_t ----------------
__global__ __launch_bounds__(256) void gn_apply_t_kernel(const float* __restrict__ in,
                                                         const float* __restrict__ stats,
                                                         const float* __restrict__ gw,
                                                         const float* __restrict__ gb,
                                                         short* __restrict__ actt) {
  __shared__ float tile[48 * 193];
  int bh = blockIdx.x;
  int b = bh / NH;
  int h = bh - b * NH;
  int tid = threadIdx.x;
  for (int i = tid; i < 2304; i += 256) {
    int c = i / 12;
    int w = (i % 12) * 4;
    float4 v = *(const float4*)(in + (((size_t)b * NC + c) * NH + h) * NW + w);
    float mean = stats[(b * NGROUPS + c / CPG) * 2];
    float rstd = stats[(b * NGROUPS + c / CPG) * 2 + 1];
    float sc = rstd * gw[c];
    float sh = gb[c] - mean * sc;
    float y;
    y = v.x * sc + sh; tile[(w + 0) * 193 + c] = y / (1.f + __expf(-y));
    y = v.y * sc + sh; tile[(w + 1) * 193 + c] = y / (1.f + __expf(-y));
    y = v.z * sc + sh; tile[(w + 2) * 193 + c] = y / (1.f + __expf(-y));
    y = v.w * sc + sh; tile[(w + 3) * 193 + c] = y / (1.f + __expf(-y));
  }
  __syncthreads();
  short* dst = actt + (((size_t)b * PH + h + 1) * PWS + 1) * NC;
  for (int i = tid; i < 2304; i += 256) {
    int w  = i / 48;
    int c4 = (i - w * 48) * 4;
    s16x4 o;
    o.x = f2bf(tile[w * 193 + c4 + 0]);
    o.y = f2bf(tile[w * 193 + c4 + 1]);
    o.z = f2bf(tile[w * 193 + c4 + 2]);
    o.w = f2bf(tile[w * 193 + c4 + 3]);
    *(s16x4*)(dst + (size_t)w * NC + c4) = o;
  }
}

// ---------------- transpose-convert: f32 [b][c][p] -> bf16 [b][p][192] ----------------
__global__ __launch_bounds__(256) void tconv_kernel(const float* __restrict__ in,
                                                    short* __restrict__ xT) {
  __shared__ float tile[48 * 193];
  int bh = blockIdx.x;
  int b = bh / NH;
  int h = bh - b * NH;
  int tid = threadIdx.x;
  for (int i = tid; i < 2304; i += 256) {
    int c = i / 12;
    int w = (i % 12) * 4;
    float4 v = *(const float4*)(in + (((size_t)b * NC + c) * NH + h) * NW + w);
    tile[(w + 0) * 193 + c] = v.x;
    tile[(w + 1) * 193 + c] = v.y;
    tile[(w + 2) * 193 + c] = v.z;
    tile[(w + 3) * 193 + c] = v.w;
  }
  __syncthreads();
  short* dst = xT + (size_t)(b * NP + h * NW) * NC;
  for (int i = tid; i < 2304; i += 256) {
    int w  = i / 48;
    int c4 = (i - w * 48) * 4;
    s16x4 o;
    o.x = f2bf(tile[w * 193 + c4 + 0]);
    o.y = f2bf(tile[w * 193 + c4 + 1]);
    o.z = f2bf(tile[w * 193 + c4 + 2]);
    o.w = f2bf(tile[w * 193 + c4 + 3]);
    *(s16x4*)(dst + (size_t)w * NC + c4) = o;
  }
}

// ---------------- 1x1 conv via MFMA: [NM*16 out x 192] @ xT[b][p][192] ----------------
// grid (36, NB), block 256 = 4 waves x 16 px. D: col=lane&15 (p), row=(lane>>4)*4+r (o).
// m=0 -> KQ[p][32] (o 0..15, upper 16 zeroed); m=1 (kv only) -> VTb[o-16][p].
template <int NM, bool ISKV>
__global__ __launch_bounds__(256) void qkv_mfma_kernel(const short* __restrict__ xT,
                                                       const short* __restrict__ aw,
                                                       short* __restrict__ KQ,
                                                       short* __restrict__ VTb) {
  int b    = blockIdx.y;
  int lane = threadIdx.x & 63;
  int wv   = threadIdx.x >> 6;
  int g    = lane >> 4, ql = lane & 15;
  int p    = blockIdx.x * 64 + wv * 16 + ql;

  f32x4 acc[NM];
#pragma unroll
  for (int m = 0; m < NM; ++m) acc[m] = (f32x4){0.f, 0.f, 0.f, 0.f};

  const short* bp = xT + ((size_t)b * NP + p) * NC + g * 8;
#pragma unroll
  for (int kc = 0; kc < 6; ++kc) {
    s16x8 bf = *(const s16x8*)(bp + kc * 32);
#pragma unroll
    for (int m = 0; m < NM; ++m) {
      s16x8 af = *(const s16x8*)(aw + ((size_t)(kc * NM + m) * 64 + lane) * 8);
      acc[m] = __builtin_amdgcn_mfma_f32_16x16x32_bf16(af, bf, acc[m], 0, 0, 0);
    }
  }
  s16x4 o0;
  o0.x = f2bf(acc[0][0]); o0.y = f2bf(acc[0][1]);
  o0.z = f2bf(acc[0][2]); o0.w = f2bf(acc[0][3]);
  *(s16x4*)(KQ + ((size_t)b * NP + p) * 32 + g * 4) = o0;
  *(s16x4*)(KQ + ((size_t)b * NP + p) * 32 + 16 + g * 4) = (s16x4){0, 0, 0, 0};
  if (ISKV) {
#pragma unroll
    for (int r = 0; r < 4; ++r)
      VTb[((size_t)b * 16 + g * 4 + r) * NP + p] = f2bf(acc[NM - 1][r]);
  }
}

// ---------------- conv3x3 via MFMA (tap-decomposed implicit GEMM), CI=192 ----------------
template <bool AFFINE, bool RESID>
__global__ __launch_bounds__(256) void conv_mfma_kernel(const short* __restrict__ actt,
                                                        const short* __restrict__ wbuf,
                                                        const float* __restrict__ bias,
                                                        const float* __restrict__ gbsum,
                                                        const float* __restrict__ resid,
                                                        float* __restrict__ out) {
  __shared__ short S[4][50][40];
  int bs = blockIdx.x;
  int b = bs / 24;
  int strip = bs - b * 24;
  int coB = blockIdx.y;
  int h0 = strip * 2;
  int tid = threadIdx.x;
  int lane = tid & 63, wave = tid >> 6;
  int wy = wave >> 1, wx = wave & 1;
  int g8 = (lane >> 4) * 8;

  f32x4 acc[2][3];
#pragma unroll
  for (int m = 0; m < 2; ++m)
#pragma unroll
    for (int f = 0; f < 3; ++f) acc[m][f] = (f32x4){0.f, 0.f, 0.f, 0.f};

  const size_t actbase = ((size_t)b * PH + h0) * PWS * NC;

  for (int kc = 0; kc < 6; ++kc) {
    __syncthreads();
    for (int i = tid; i < 800; i += 256) {
      int ci8 = i & 3;
      int rc  = i >> 2;
      int col = rc % 50, r = rc / 50;
      const s16x8* src = (const s16x8*)(actt + actbase + ((size_t)r * PWS + col) * NC +
                                        kc * 32 + ci8 * 8);
      *(s16x8*)(&S[r][col][ci8 * 8]) = *src;
    }
    __syncthreads();
#pragma unroll
    for (int t = 0; t < 9; ++t) {
      int ky = t / 3, kx = t - ky * 3;
      const short* wp = wbuf + ((((size_t)kc * 9 + t) * 12 + (coB * 4 + wy * 2)) * 64 + lane) * 8;
      s16x8 a0 = *(const s16x8*)wp;
      s16x8 a1 = *(const s16x8*)(wp + 64 * 8);
      int row = wx + ky;
#pragma unroll
      for (int f = 0; f < 3; ++f) {
        int col = f * 16 + (lane & 15) + kx;
        s16x8 bf = *(const s16x8*)(&S[row][col][g8]);
        acc[0][f] = __builtin_amdgcn_mfma_f32_16x16x32_bf16(a0, bf, acc[0][f], 0, 0, 0);
        acc[1][f] = __builtin_amdgcn_mfma_f32_16x16x32_bf16(a1, bf, acc[1][f], 0, 0, 0);
      }
    }
  }
  int hout = h0 + wx;
#pragma unroll
  for (int m = 0; m < 2; ++m) {
    int co0 = coB * 64 + wy * 32 + m * 16;
#pragma unroll
    for (int r = 0; r < 4; ++r) {
      int co = co0 + (lane >> 4) * 4 + r;
      float bv = bias[co];
      float s = AFFINE ? gbsum[b * NC + co] : 0.f;
#pragma unroll
      for (int f = 0; f < 3; ++f) {
        int w = f * 16 + (lane & 15);
        size_t o = (((size_t)b * NC + co) * NH + hout) * NW + w;
        float v = acc[m][f][r] + bv;
        if (AFFINE) v = v * (1.f + s) + s;
        if (RESID) v += resid[o];
        out[o] = v;
      }
    }
  }
}

// ---------------- out conv 3x3 via MFMA, CI=16 (zero-padded to 32), in-place resid ----
__global__ __launch_bounds__(256) void out_conv_mfma_kernel(const short* __restrict__ aot,
                                                            const short* __restrict__ wbuf,
                                                            const float* __restrict__ bias,
                                                            float* __restrict__ out) {
  __shared__ short S[4][50][40];
  int bs = blockIdx.x;
  int b = bs / 24;
  int strip = bs - b * 24;
  int coB = blockIdx.y;
  int h0 = strip * 2;
  int tid = threadIdx.x;
  int lane = tid & 63, wave = tid >> 6;
  int wy = wave >> 1, wx = wave & 1;
  int g8 = (lane >> 4) * 8;

  f32x4 acc[2][3];
#pragma unroll
  for (int m = 0; m < 2; ++m)
#pragma unroll
    for (int f = 0; f < 3; ++f) acc[m][f] = (f32x4){0.f, 0.f, 0.f, 0.f};

  const size_t base = ((size_t)b * PH + h0) * PWS * 16;
  for (int i = tid; i < 800; i += 256) {
    int ci8 = i & 3;
    int rc  = i >> 2;
    int col = rc % 50, r = rc / 50;
    s16x8 v = (s16x8){0, 0, 0, 0, 0, 0, 0, 0};
    if (ci8 < 2)
      v = *(const s16x8*)(aot + base + ((size_t)r * PWS + col) * 16 + ci8 * 8);
    *(s16x8*)(&S[r][col][ci8 * 8]) = v;
  }
  __syncthreads();
#pragma unroll
  for (int t = 0; t < 9; ++t) {
    int ky = t / 3, kx = t - ky * 3;
    const short* wp = wbuf + (((size_t)t * 12 + (coB * 4 + wy * 2)) * 64 + lane) * 8;
    s16x8 a0 = *(const s16x8*)wp;
    s16x8 a1 = *(const s16x8*)(wp + 64 * 8);
    int row = wx + ky;
#pragma unroll
    for (int f = 0; f < 3; ++f) {
      int col = f * 16 + (lane & 15) + kx;
      s16x8 bf = *(const s16x8*)(&S[row][col][g8]);
      acc[0][f] = __builtin_amdgcn_mfma_f32_16x16x32_bf16(a0, bf, acc[0][f], 0, 0, 0);
      acc[1][f] = __builtin_amdgcn_mfma_f32_16x16x32_bf16(a1, bf, acc[1][f], 0, 0, 0);
    }
  }
  int hout = h0 + wx;
#pragma unroll
  for (int m = 0; m < 2; ++m) {
    int co0 = coB * 64 + wy * 32 + m * 16;
#pragma unroll
    for (int r = 0; r < 4; ++r) {
      int co = co0 + (lane >> 4) * 4 + r;
      float bv = bias[co];
#pragma unroll
      for (int f = 0; f < 3; ++f) {
        int w = f * 16 + (lane & 15);
        size_t o = (((size_t)b * NC + co) * NH + hout) * NW + w;
        out[o] = acc[m][f][r] + bv + out[o];
      }
    }
  }
}

// ---------------- MFMA flash attention, KS=4 key-split + defer-max ----------------
__global__ __launch_bounds__(1024) void attn_mfma_kernel(const short* __restrict__ Qb,
                                                         const short* __restrict__ Kb,
                                                         const short* __restrict__ VTb,
                                                         short* __restrict__ aot) {
  __shared__ float PM[4][4][64], PL[4][4][64];
  __shared__ f32x4 PA[4][4][64];
  int b    = blockIdx.y;
  int tid  = threadIdx.x;
  int lane = tid & 63;
  int w    = tid >> 6;
  int qg   = w & 3, ks = w >> 2;
  int q0   = blockIdx.x * 64 + qg * 16;
  int g    = lane >> 4;
  int ql   = lane & 15;

  s16x8 qfrag = *(const s16x8*)(Qb + ((size_t)b * NP + q0 + ql) * 32 + g * 8);

  int r0 = 8 * (ql >> 2) + (ql & 3);
  const short* Kbase = Kb + (size_t)b * NP * 32 + g * 8;
  const short* Vbase = VTb + ((size_t)b * 16 + ql) * NP;

  f32x4 acc = {0.f, 0.f, 0.f, 0.f};
  float m = -1e30f, l = 0.f;

  int kk = ks * 576;
  s16x8 kf0 = *(const s16x8*)(Kbase + (size_t)(kk + r0) * 32);
  s16x8 kf1 = *(const s16x8*)(Kbase + (size_t)(kk + r0 + 4) * 32);
  s16x8 vf  = *(const s16x8*)(Vbase + kk + g * 8);

  for (int step = 0; step < 18; ++step) {
    int kn = (step < 17) ? kk + 32 : ks * 576;
    s16x8 nk0 = *(const s16x8*)(Kbase + (size_t)(kn + r0) * 32);
    s16x8 nk1 = *(const s16x8*)(Kbase + (size_t)(kn + r0 + 4) * 32);
    s16x8 nv  = *(const s16x8*)(Vbase + kn + g * 8);

    f32x4 z = {0.f, 0.f, 0.f, 0.f};
    f32x4 s0 = __builtin_amdgcn_mfma_f32_16x16x32_bf16(kf0, qfrag, z, 0, 0, 0);
    f32x4 s1 = __builtin_amdgcn_mfma_f32_16x16x32_bf16(kf1, qfrag, z, 0, 0, 0);

    float tm = fmaxf(fmaxf(fmaxf(s0[0], s0[1]), fmaxf(s0[2], s0[3])),
                     fmaxf(fmaxf(s1[0], s1[1]), fmaxf(s1[2], s1[3])));
    if (!__all(tm <= m + 8.0f)) {
      tm = fmaxf(tm, __shfl_xor(tm, 16, 64));
      tm = fmaxf(tm, __shfl_xor(tm, 32, 64));
      float mn = fmaxf(m, tm);
      float corr = exp2f(m - mn);
      m = mn;
      l *= corr;
      acc[0] *= corr; acc[1] *= corr; acc[2] *= corr; acc[3] *= corr;
    }
    float p0 = exp2f(s0[0] - m), p1 = exp2f(s0[1] - m);
    float p2 = exp2f(s0[2] - m), p3 = exp2f(s0[3] - m);
    float p4 = exp2f(s1[0] - m), p5 = exp2f(s1[1] - m);
    float p6 = exp2f(s1[2] - m), p7 = exp2f(s1[3] - m);
    l += ((p0 + p1) + (p2 + p3)) + ((p4 + p5) + (p6 + p7));

    s16x8 pf;
    pf[0] = f2bf(p0); pf[1] = f2bf(p1); pf[2] = f2bf(p2); pf[3] = f2bf(p3);
    pf[4] = f2bf(p4); pf[5] = f2bf(p5); pf[6] = f2bf(p6); pf[7] = f2bf(p7);
    acc = __builtin_amdgcn_mfma_f32_16x16x32_bf16(vf, pf, acc, 0, 0, 0);

    kf0 = nk0; kf1 = nk1; vf = nv; kk = kn;
  }
  PM[ks][qg][lane] = m;
  PL[ks][qg][lane] = l;
  PA[ks][qg][lane] = acc;
  __syncthreads();
  if (ks == 0) {
    float M = PM[0][qg][lane];
#pragma unroll
    for (int k = 1; k < 4; ++k) M = fmaxf(M, PM[k][qg][lane]);
    float L = 0.f;
    f32x4 o = {0.f, 0.f, 0.f, 0.f};
#pragma unroll
    for (int k = 0; k < 4; ++k) {
      float c = exp2f(PM[k][qg][lane] - M);
      L += PL[k][qg][lane] * c;
      f32x4 a = PA[k][qg][lane];
      o[0] += a[0] * c; o[1] += a[1] * c; o[2] += a[2] * c; o[3] += a[3] * c;
    }
    L += __shfl_xor(L, 16, 64);
    L += __shfl_xor(L, 32, 64);
    float inv = 1.f / L;
    int q = q0 + ql;
    int h = q / NW, wcol = q - h * NW;
    s16x4 ov;
    ov.x = f2bf(o[0] * inv);
    ov.y = f2bf(o[1] * inv);
    ov.z = f2bf(o[2] * inv);
    ov.w = f2bf(o[3] * inv);
    *(s16x4*)(aot + (((size_t)b * PH + h + 1) * PWS + wcol + 1) * 16 + g * 4) = ov;
  }
}

// ---------------- launch ----------------
extern "C" void kernel_launch(void* const* d_in, const int* in_sizes, int n_in,
                              void* d_out, int out_size, void* d_ws, size_t ws_size,
                              hipStream_t stream) {
  const float* x      = (const float*)d_in[0];
  const float* xe     = (const float*)d_in[1];
  const float* temb   = (const float*)d_in[2];
  const float* gn1w   = (const float*)d_in[3];
  const float* gn1b   = (const float*)d_in[4];
  const float* conv1w = (const float*)d_in[5];
  const float* conv1b = (const float*)d_in[6];
  const float* affw   = (const float*)d_in[7];
  const float* affb   = (const float*)d_in[8];
  const float* gn2w   = (const float*)d_in[9];
  const float* gn2b   = (const float*)d_in[10];
  const float* conv2w = (const float*)d_in[11];
  const float* conv2b = (const float*)d_in[12];
  const float* qw     = (const float*)d_in[13];
  const float* kvw    = (const float*)d_in[14];
  const float* outw   = (const float*)d_in[15];
  const float* outb   = (const float*)d_in[16];
  float* out = (float*)d_out;
  float* ws  = (float*)d_ws;

  const float SC = 0.36067376022224085f;  // 0.25 * log2(e)

  // ws layout (f32 region first, then bf16 region)
  float* gbsum  = ws;                                    // 1,536
  float* stats  = gbsum + NB * NC;                       // 512
  float* gnpart = stats + 512;                           // 256*6*2 = 3,072
  short* wbuf1  = (short*)(gnpart + 3072);                      // 331,776 bf16
  short* wbuf2  = wbuf1 + (size_t)6 * 9 * 12 * 64 * 8;          // 331,776 bf16
  short* wbufo  = wbuf2 + (size_t)6 * 9 * 12 * 64 * 8;          // 55,296 bf16
  short* awq    = wbufo + (size_t)9 * 12 * 64 * 8;              // 3,072 bf16
  short* awkv   = awq + 3072;                                   // 6,144 bf16
  short* actt   = awkv + 6144;                                  // 3,993,600 bf16
  short* Qb     = actt + ACT_T_ELEMS;                           // 589,824 bf16
  short* Kb     = Qb + (size_t)NB * NP * 32;                    // 589,824 bf16
  short* VTb    = Kb + (size_t)NB * NP * 32;                    // 294,912 bf16
  short* aot    = VTb + (size_t)NB * 16 * NP;                   // 332,800 bf16
  short* xeT    = aot + AOT_ELEMS;                              // 3,538,944 bf16
  short* xrT    = xeT + (size_t)NB * NP * NC;                   // 3,538,944 bf16

  // prep (weights, affine, halos)
  wprep_kernel<<<1296, 256, 0, stream>>>(conv1w, wbuf1);
  wprep_kernel<<<1296, 256, 0, stream>>>(conv2w, wbuf2);
  wprep_o_kernel<<<216, 256, 0, stream>>>(outw, wbufo);
  wprep_a_kernel<1><<<12, 256, 0, stream>>>(qw, awq, SC);
  wprep_a_kernel<2><<<24, 256, 0, stream>>>(kvw, awkv, 1.0f);
  affine_kernel<<<6, 256, 0, stream>>>(temb, affw, affb, gbsum);
  halo_zero_kernel<<<dim3(38, NB), 256, 0, stream>>>(actt);
  halo_zero16_kernel<<<NB, 256, 0, stream>>>(aot);

  // kv path (independent of resnet chain) — run early
  tconv_kernel<<<NB * NH, 256, 0, stream>>>(xe, xeT);
  qkv_mfma_kernel<2, true><<<dim3(36, NB), 256, 0, stream>>>(xeT, awkv, Kb, VTb);

  // ----- ResnetBlock -----
  gn_stats_part_kernel<<<dim3(NB * NGROUPS, 6), 192, 0, stream>>>(x, gnpart);
  gn_stats_reduce_kernel<<<1, 256, 0, stream>>>(gnpart, stats);
  gn_apply_t_kernel<<<NB * NH, 256, 0, stream>>>(x, stats, gn1w, gn1b, actt);
  conv_mfma_kernel<true, false><<<dim3(NB * 24, 3), 256, 0, stream>>>(
      actt, wbuf1, conv1b, gbsum, nullptr, out);
  gn_stats_part_kernel<<<dim3(NB * NGROUPS, 6), 192, 0, stream>>>(out, gnpart);
  gn_stats_reduce_kernel<<<1, 256, 0, stream>>>(gnpart, stats);
  gn_apply_t_kernel<<<NB * NH, 256, 0, stream>>>(out, stats, gn2w, gn2b, actt);
  conv_mfma_kernel<false, true><<<dim3(NB * 24, 3), 256, 0, stream>>>(
      actt, wbuf2, conv2b, nullptr, x, out);

  // ----- CrossAttention -----
  tconv_kernel<<<NB * NH, 256, 0, stream>>>(out, xrT);
  qkv_mfma_kernel<1, false><<<dim3(36, NB), 256, 0, stream>>>(xrT, awq, Qb, nullptr);
  attn_mfma_kernel<<<dim3(36, NB), 1024, 0, stream>>>(Qb, Kb, VTb, aot);
  out_conv_mfma_kernel<<<dim3(NB * 24, 3), 256, 0, stream>>>(aot, wbufo, outb, out);
}

// Round 10
// 250.425 us; speedup vs baseline: 4.1854x; 1.1013x over previous
//
#include <hip/hip_runtime.h>
#include <hip/hip_bf16.h>

#define NB 8
#define NC 192
#define NH 48
#define NW 48
#define NP 2304        // 48*48
#define NGROUPS 32
#define CPG 6          // NC/NGROUPS
#define NEMB 192
#define NCQ 16

// padded-transposed activation: [B][50 h'][52 w' stride (50 used)][192 c] bf16
#define PH 50
#define PWS 52
#define ACT_T_ELEMS ((size_t)NB * PH * PWS * NC)   // 3,993,600 bf16
#define AOT_ELEMS   ((size_t)NB * PH * PWS * 16)   // 332,800 bf16

typedef __attribute__((ext_vector_type(4))) short s16x4;
typedef __attribute__((ext_vector_type(8))) short s16x8;
typedef __attribute__((ext_vector_type(4))) float f32x4;

static __device__ inline short f2bf(float v) {
  __hip_bfloat16 h = __float2bfloat16(v);
  return *(short*)&h;
}

// ---------------- mega-prep: all weight reorders + affine + halo zeros in one kernel ----
// block ranges: [0,1296) wprep1 | [1296,2592) wprep2 | [2592,2808) wprep_o |
// [2808,2820) awq | [2820,2844) awkv | [2844,2850) affine | [2850,3154) halo |
// [3154,3162) halo16
__global__ __launch_bounds__(256) void megaprep_kernel(
    const float* __restrict__ conv1w, const float* __restrict__ conv2w,
    const float* __restrict__ outw, const float* __restrict__ qw,
    const float* __restrict__ kvw, const float* __restrict__ emb,
    const float* __restrict__ affw, const float* __restrict__ affb,
    short* __restrict__ wbuf1, short* __restrict__ wbuf2, short* __restrict__ wbufo,
    short* __restrict__ awq, short* __restrict__ awkv,
    float* __restrict__ gbsum, short* __restrict__ actt, short* __restrict__ aot) {
  int bx = blockIdx.x;
  int tid = threadIdx.x;
  const float SC = 0.36067376022224085f;  // 0.25 * log2(e)
  if (bx < 2592) {                        // conv1/conv2 3x3 weight prep
    const float* w = (bx < 1296) ? conv1w : conv2w;
    short* wb      = (bx < 1296) ? wbuf1 : wbuf2;
    int i = ((bx < 1296) ? bx : bx - 1296) * 256 + tid;
    int j  = i & 7;
    int l  = (i >> 3) & 63;
    int cf = (i >> 9) % 12;
    int tk = (i >> 9) / 12;
    int t  = tk % 9;
    int kc = tk / 9;
    int co = cf * 16 + (l & 15);
    int ci = kc * 32 + (l >> 4) * 8 + j;
    wb[i] = f2bf(w[((size_t)co * NC + ci) * 9 + t]);
  } else if (bx < 2808) {                 // out-conv weight prep (CI=16 pad to 32)
    int i = (bx - 2592) * 256 + tid;
    int j  = i & 7;
    int l  = (i >> 3) & 63;
    int cf = (i >> 9) % 12;
    int t  = (i >> 9) / 12;
    int co = cf * 16 + (l & 15);
    int ci = (l >> 4) * 8 + j;
    wbufo[i] = (ci < 16) ? f2bf(outw[((size_t)co * 16 + ci) * 9 + t]) : (short)0;
  } else if (bx < 2820) {                 // q 1x1 weights (scale folded), NM=1
    int i = (bx - 2808) * 256 + tid;
    int j = i & 7, l = (i >> 3) & 63, rest = i >> 9;
    int kc = rest;                        // NM=1 -> m=0
    int co = (l & 15);
    int ci = kc * 32 + (l >> 4) * 8 + j;
    awq[i] = f2bf(qw[(size_t)co * NC + ci] * SC);
  } else if (bx < 2844) {                 // kv 1x1 weights, NM=2
    int i = (bx - 2820) * 256 + tid;
    int j = i & 7, l = (i >> 3) & 63, rest = i >> 9;
    int m = rest % 2, kc = rest / 2;
    int co = m * 16 + (l & 15);
    int ci = kc * 32 + (l >> 4) * 8 + j;
    awkv[i] = f2bf(kvw[(size_t)co * NC + ci]);
  } else if (bx < 2850) {                 // FeatureWiseAffine GEMV
    int i = (bx - 2844) * 256 + tid;
    if (i < NB * NC) {
      int b = i / NC;
      int c = i - b * NC;
      const float* e  = emb + b * NEMB;
      const float* w0 = affw + c * NEMB;
      const float* w1 = affw + (c + NC) * NEMB;
      float s = 0.f;
      for (int j = 0; j < NEMB; ++j) s += e[j] * (w0[j] + w1[j]);
      gbsum[i] = 0.5f * (s + affb[c] + affb[c + NC]);
    }
  } else if (bx < 3154) {                 // actt halo zero
    int rel = bx - 2850;
    int b = rel / 38, xb = rel - b * 38;
    int i = xb * 256 + tid;
    if (i < 9600) {
      int c4 = i % 48;
      int r  = i / 48;
      size_t off;
      if (r < 52)       off = ((size_t)0 * PWS + r) * NC;
      else if (r < 104) off = ((size_t)49 * PWS + (r - 52)) * NC;
      else if (r < 152) off = ((size_t)(r - 104 + 1) * PWS + 0) * NC;
      else              off = ((size_t)(r - 152 + 1) * PWS + 49) * NC;
      *(s16x4*)(&actt[(size_t)b * PH * PWS * NC + off + c4 * 4]) = (s16x4){0, 0, 0, 0};
    }
  } else {                                // aot halo zero
    int b = bx - 3154;
    for (int i = tid; i < 784; i += 256) {
      int c4  = i & 3;
      int pos = i >> 2;
      int r, col;
      if (pos < 50)       { r = 0;  col = pos; }
      else if (pos < 100) { r = 49; col = pos - 50; }
      else if (pos < 148) { r = pos - 100 + 1; col = 0; }
      else                { r = pos - 148 + 1; col = 49; }
      *(s16x4*)(&aot[(((size_t)b * PH + r) * PWS + col) * 16 + c4 * 4]) = (s16x4){0, 0, 0, 0};
    }
  }
}

// ---------------- GroupNorm stats, split grid: partial sums ----------------
__global__ __launch_bounds__(192) void gn_stats_part_kernel(const float* __restrict__ in,
                                                            float* __restrict__ part) {
  int bg = blockIdx.x, seg = blockIdx.y;  // 256 groups x 6 segments of 2304 floats
  const float4* p = (const float4*)(in + (size_t)bg * (CPG * NP) + seg * 2304);
  float s = 0.f, s2 = 0.f;
  for (int i = threadIdx.x; i < 576; i += 192) {
    float4 v = p[i];
    s  += v.x + v.y + v.z + v.w;
    s2 += v.x * v.x + v.y * v.y + v.z * v.z + v.w * v.w;
  }
#pragma unroll
  for (int off = 32; off > 0; off >>= 1) {
    s  += __shfl_down(s, off);
    s2 += __shfl_down(s2, off);
  }
  __shared__ float red[6];
  int wave = threadIdx.x >> 6;
  if ((threadIdx.x & 63) == 0) { red[wave * 2] = s; red[wave * 2 + 1] = s2; }
  __syncthreads();
  if (threadIdx.x == 0) {
    part[(bg * 6 + seg) * 2]     = red[0] + red[2] + red[4];
    part[(bg * 6 + seg) * 2 + 1] = red[1] + red[3] + red[5];
  }
}

// ---------------- GN apply + swish -> padded TRANSPOSED bf16 act_t (inline stats) ------
__global__ __launch_bounds__(256) void gn_apply_t_kernel(const float* __restrict__ in,
                                                         const float* __restrict__ gnpart,
                                                         const float* __restrict__ gw,
                                                         const float* __restrict__ gb,
                                                         short* __restrict__ actt) {
  __shared__ float tile[48 * 193];
  __shared__ float sst[32][2];
  int bh = blockIdx.x;
  int b = bh / NH;
  int h = bh - b * NH;
  int tid = threadIdx.x;
  if (tid < 32) {
    float S = 0.f, S2 = 0.f;
#pragma unroll
    for (int k = 0; k < 6; ++k) {
      S  += gnpart[((b * 32 + tid) * 6 + k) * 2];
      S2 += gnpart[((b * 32 + tid) * 6 + k) * 2 + 1];
    }
    const float invN = 1.f / (float)(CPG * NP);
    float mean = S * invN;
    float var  = S2 * invN - mean * mean;
    sst[tid][0] = mean;
    sst[tid][1] = rsqrtf(var + 1e-5f);
  }
  __syncthreads();
  for (int i = tid; i < 2304; i += 256) {
    int c = i / 12;
    int w = (i % 12) * 4;
    float4 v = *(const float4*)(in + (((size_t)b * NC + c) * NH + h) * NW + w);
    float sc = sst[c / CPG][1] * gw[c];
    float sh = gb[c] - sst[c / CPG][0] * sc;
    float y;
    y = v.x * sc + sh; tile[(w + 0) * 193 + c] = y / (1.f + __expf(-y));
    y = v.y * sc + sh; tile[(w + 1) * 193 + c] = y / (1.f + __expf(-y));
    y = v.z * sc + sh; tile[(w + 2) * 193 + c] = y / (1.f + __expf(-y));
    y = v.w * sc + sh; tile[(w + 3) * 193 + c] = y / (1.f + __expf(-y));
  }
  __syncthreads();
  short* dst = actt + (((size_t)b * PH + h + 1) * PWS + 1) * NC;
  for (int i = tid; i < 2304; i += 256) {
    int w  = i / 48;
    int c4 = (i - w * 48) * 4;
    s16x4 o;
    o.x = f2bf(tile[w * 193 + c4 + 0]);
    o.y = f2bf(tile[w * 193 + c4 + 1]);
    o.z = f2bf(tile[w * 193 + c4 + 2]);
    o.w = f2bf(tile[w * 193 + c4 + 3]);
    *(s16x4*)(dst + (size_t)w * NC + c4) = o;
  }
}

// ---------------- fused transpose + 1x1 conv via MFMA ----------------
// grid (NB*NH), 192 thr = 3 waves x 16 px. Phase 1: f32 [c][48 px row] -> LDS [px][c]
// (stride 193, conflict-free). Phase 2: B-frags from LDS, A-frags (weights) from L2.
template <int NM, bool ISKV>
__global__ __launch_bounds__(192) void qkv_fused_kernel(const float* __restrict__ X,
                                                        const short* __restrict__ aw,
                                                        short* __restrict__ KQ,
                                                        short* __restrict__ VTb) {
  __shared__ float tile[48 * 193];
  int bh = blockIdx.x;
  int b = bh / NH;
  int h = bh - b * NH;
  int tid = threadIdx.x;
  for (int i = tid; i < 2304; i += 192) {
    int c = i / 12;
    int w = (i % 12) * 4;
    float4 v = *(const float4*)(X + (((size_t)b * NC + c) * NH + h) * NW + w);
    tile[(w + 0) * 193 + c] = v.x;
    tile[(w + 1) * 193 + c] = v.y;
    tile[(w + 2) * 193 + c] = v.z;
    tile[(w + 3) * 193 + c] = v.w;
  }
  __syncthreads();
  int lane = tid & 63, wv = tid >> 6;
  int g = lane >> 4, ql = lane & 15;
  int pxl = wv * 16 + ql;                 // 0..47 within the row
  int p   = h * NW + pxl;                 // global spatial index

  f32x4 acc[NM];
#pragma unroll
  for (int m = 0; m < NM; ++m) acc[m] = (f32x4){0.f, 0.f, 0.f, 0.f};

  const float* bp = &tile[pxl * 193 + g * 8];
#pragma unroll
  for (int kc = 0; kc < 6; ++kc) {
    s16x8 bf;
#pragma unroll
    for (int j = 0; j < 8; ++j) bf[j] = f2bf(bp[kc * 32 + j]);
#pragma unroll
    for (int m = 0; m < NM; ++m) {
      s16x8 af = *(const s16x8*)(aw + ((size_t)(kc * NM + m) * 64 + lane) * 8);
      acc[m] = __builtin_amdgcn_mfma_f32_16x16x32_bf16(af, bf, acc[m], 0, 0, 0);
    }
  }
  s16x4 o0;
  o0.x = f2bf(acc[0][0]); o0.y = f2bf(acc[0][1]);
  o0.z = f2bf(acc[0][2]); o0.w = f2bf(acc[0][3]);
  *(s16x4*)(KQ + ((size_t)b * NP + p) * 32 + g * 4) = o0;
  *(s16x4*)(KQ + ((size_t)b * NP + p) * 32 + 16 + g * 4) = (s16x4){0, 0, 0, 0};
  if (ISKV) {
#pragma unroll
    for (int r = 0; r < 4; ++r)
      VTb[((size_t)b * 16 + g * 4 + r) * NP + p] = f2bf(acc[NM - 1][r]);
  }
}

// ---------------- conv3x3 via MFMA, CI=192, double-buffered LDS staging ----------------
template <bool AFFINE, bool RESID>
__global__ __launch_bounds__(256) void conv_mfma_kernel(const short* __restrict__ actt,
                                                        const short* __restrict__ wbuf,
                                                        const float* __restrict__ bias,
                                                        const float* __restrict__ gbsum,
                                                        const float* __restrict__ resid,
                                                        float* __restrict__ out) {
  __shared__ short S[2][4][50][40];       // 32 KB double buffer
  int bs = blockIdx.x;
  int b = bs / 24;
  int strip = bs - b * 24;
  int coB = blockIdx.y;
  int h0 = strip * 2;
  int tid = threadIdx.x;
  int lane = tid & 63, wave = tid >> 6;
  int wy = wave >> 1, wx = wave & 1;
  int g8 = (lane >> 4) * 8;

  f32x4 acc[2][3];
#pragma unroll
  for (int m = 0; m < 2; ++m)
#pragma unroll
    for (int f = 0; f < 3; ++f) acc[m][f] = (f32x4){0.f, 0.f, 0.f, 0.f};

  const size_t actbase = ((size_t)b * PH + h0) * PWS * NC;

  auto stage = [&](int buf, int kc) {
    for (int i = tid; i < 800; i += 256) {
      int ci8 = i & 3;
      int rc  = i >> 2;
      int col = rc % 50, r = rc / 50;
      const s16x8* src = (const s16x8*)(actt + actbase + ((size_t)r * PWS + col) * NC +
                                        kc * 32 + ci8 * 8);
      *(s16x8*)(&S[buf][r][col][ci8 * 8]) = *src;
    }
  };

  stage(0, 0);
  __syncthreads();
  for (int kc = 0; kc < 6; ++kc) {
    if (kc < 5) stage((kc + 1) & 1, kc + 1);   // issue next-tile loads before compute
    int cur = kc & 1;
#pragma unroll
    for (int t = 0; t < 9; ++t) {
      int ky = t / 3, kx = t - ky * 3;
      const short* wp = wbuf + ((((size_t)kc * 9 + t) * 12 + (coB * 4 + wy * 2)) * 64 + lane) * 8;
      s16x8 a0 = *(const s16x8*)wp;
      s16x8 a1 = *(const s16x8*)(wp + 64 * 8);
      int row = wx + ky;
#pragma unroll
      for (int f = 0; f < 3; ++f) {
        int col = f * 16 + (lane & 15) + kx;
        s16x8 bf = *(const s16x8*)(&S[cur][row][col][g8]);
        acc[0][f] = __builtin_amdgcn_mfma_f32_16x16x32_bf16(a0, bf, acc[0][f], 0, 0, 0);
        acc[1][f] = __builtin_amdgcn_mfma_f32_16x16x32_bf16(a1, bf, acc[1][f], 0, 0, 0);
      }
    }
    __syncthreads();
  }
  int hout = h0 + wx;
#pragma unroll
  for (int m = 0; m < 2; ++m) {
    int co0 = coB * 64 + wy * 32 + m * 16;
#pragma unroll
    for (int r = 0; r < 4; ++r) {
      int co = co0 + (lane >> 4) * 4 + r;
      float bv = bias[co];
      float s = AFFINE ? gbsum[b * NC + co] : 0.f;
#pragma unroll
      for (int f = 0; f < 3; ++f) {
        int w = f * 16 + (lane & 15);
        size_t o = (((size_t)b * NC + co) * NH + hout) * NW + w;
        float v = acc[m][f][r] + bv;
        if (AFFINE) v = v * (1.f + s) + s;
        if (RESID) v += resid[o];
        out[o] = v;
      }
    }
  }
}

// ---------------- out conv 3x3 via MFMA, CI=16 (zero-padded to 32), in-place resid ----
__global__ __launch_bounds__(256) void out_conv_mfma_kernel(const short* __restrict__ aot,
                                                            const short* __restrict__ wbuf,
                                                            const float* __restrict__ bias,
                                                            float* __restrict__ out) {
  __shared__ short S[4][50][40];
  int bs = blockIdx.x;
  int b = bs / 24;
  int strip = bs - b * 24;
  int coB = blockIdx.y;
  int h0 = strip * 2;
  int tid = threadIdx.x;
  int lane = tid & 63, wave = tid >> 6;
  int wy = wave >> 1, wx = wave & 1;
  int g8 = (lane >> 4) * 8;

  f32x4 acc[2][3];
#pragma unroll
  for (int m = 0; m < 2; ++m)
#pragma unroll
    for (int f = 0; f < 3; ++f) acc[m][f] = (f32x4){0.f, 0.f, 0.f, 0.f};

  const size_t base = ((size_t)b * PH + h0) * PWS * 16;
  for (int i = tid; i < 800; i += 256) {
    int ci8 = i & 3;
    int rc  = i >> 2;
    int col = rc % 50, r = rc / 50;
    s16x8 v = (s16x8){0, 0, 0, 0, 0, 0, 0, 0};
    if (ci8 < 2)
      v = *(const s16x8*)(aot + base + ((size_t)r * PWS + col) * 16 + ci8 * 8);
    *(s16x8*)(&S[r][col][ci8 * 8]) = v;
  }
  __syncthreads();
#pragma unroll
  for (int t = 0; t < 9; ++t) {
    int ky = t / 3, kx = t - ky * 3;
    const short* wp = wbuf + (((size_t)t * 12 + (coB * 4 + wy * 2)) * 64 + lane) * 8;
    s16x8 a0 = *(const s16x8*)wp;
    s16x8 a1 = *(const s16x8*)(wp + 64 * 8);
    int row = wx + ky;
#pragma unroll
    for (int f = 0; f < 3; ++f) {
      int col = f * 16 + (lane & 15) + kx;
      s16x8 bf = *(const s16x8*)(&S[row][col][g8]);
      acc[0][f] = __builtin_amdgcn_mfma_f32_16x16x32_bf16(a0, bf, acc[0][f], 0, 0, 0);
      acc[1][f] = __builtin_amdgcn_mfma_f32_16x16x32_bf16(a1, bf, acc[1][f], 0, 0, 0);
    }
  }
  int hout = h0 + wx;
#pragma unroll
  for (int m = 0; m < 2; ++m) {
    int co0 = coB * 64 + wy * 32 + m * 16;
#pragma unroll
    for (int r = 0; r < 4; ++r) {
      int co = co0 + (lane >> 4) * 4 + r;
      float bv = bias[co];
#pragma unroll
      for (int f = 0; f < 3; ++f) {
        int w = f * 16 + (lane & 15);
        size_t o = (((size_t)b * NC + co) * NH + hout) * NW + w;
        out[o] = acc[m][f][r] + bv + out[o];
      }
    }
  }
}

// ---------------- MFMA flash attention, KS=4 key-split + defer-max ----------------
__global__ __launch_bounds__(1024) void attn_mfma_kernel(const short* __restrict__ Qb,
                                                         const short* __restrict__ Kb,
                                                         const short* __restrict__ VTb,
                                                         short* __restrict__ aot) {
  __shared__ float PM[4][4][64], PL[4][4][64];
  __shared__ f32x4 PA[4][4][64];
  int b    = blockIdx.y;
  int tid  = threadIdx.x;
  int lane = tid & 63;
  int w    = tid >> 6;
  int qg   = w & 3, ks = w >> 2;
  int q0   = blockIdx.x * 64 + qg * 16;
  int g    = lane >> 4;
  int ql   = lane & 15;

  s16x8 qfrag = *(const s16x8*)(Qb + ((size_t)b * NP + q0 + ql) * 32 + g * 8);

  int r0 = 8 * (ql >> 2) + (ql & 3);
  const short* Kbase = Kb + (size_t)b * NP * 32 + g * 8;
  const short* Vbase = VTb + ((size_t)b * 16 + ql) * NP;

  f32x4 acc = {0.f, 0.f, 0.f, 0.f};
  float m = -1e30f, l = 0.f;

  int kk = ks * 576;
  s16x8 kf0 = *(const s16x8*)(Kbase + (size_t)(kk + r0) * 32);
  s16x8 kf1 = *(const s16x8*)(Kbase + (size_t)(kk + r0 + 4) * 32);
  s16x8 vf  = *(const s16x8*)(Vbase + kk + g * 8);

  for (int step = 0; step < 18; ++step) {
    int kn = (step < 17) ? kk + 32 : ks * 576;
    s16x8 nk0 = *(const s16x8*)(Kbase + (size_t)(kn + r0) * 32);
    s16x8 nk1 = *(const s16x8*)(Kbase + (size_t)(kn + r0 + 4) * 32);
    s16x8 nv  = *(const s16x8*)(Vbase + kn + g * 8);

    f32x4 z = {0.f, 0.f, 0.f, 0.f};
    f32x4 s0 = __builtin_amdgcn_mfma_f32_16x16x32_bf16(kf0, qfrag, z, 0, 0, 0);
    f32x4 s1 = __builtin_amdgcn_mfma_f32_16x16x32_bf16(kf1, qfrag, z, 0, 0, 0);

    float tm = fmaxf(fmaxf(fmaxf(s0[0], s0[1]), fmaxf(s0[2], s0[3])),
                     fmaxf(fmaxf(s1[0], s1[1]), fmaxf(s1[2], s1[3])));
    if (!__all(tm <= m + 8.0f)) {
      tm = fmaxf(tm, __shfl_xor(tm, 16, 64));
      tm = fmaxf(tm, __shfl_xor(tm, 32, 64));
      float mn = fmaxf(m, tm);
      float corr = exp2f(m - mn);
      m = mn;
      l *= corr;
      acc[0] *= corr; acc[1] *= corr; acc[2] *= corr; acc[3] *= corr;
    }
    float p0 = exp2f(s0[0] - m), p1 = exp2f(s0[1] - m);
    float p2 = exp2f(s0[2] - m), p3 = exp2f(s0[3] - m);
    float p4 = exp2f(s1[0] - m), p5 = exp2f(s1[1] - m);
    float p6 = exp2f(s1[2] - m), p7 = exp2f(s1[3] - m);
    l += ((p0 + p1) + (p2 + p3)) + ((p4 + p5) + (p6 + p7));

    s16x8 pf;
    pf[0] = f2bf(p0); pf[1] = f2bf(p1); pf[2] = f2bf(p2); pf[3] = f2bf(p3);
    pf[4] = f2bf(p4); pf[5] = f2bf(p5); pf[6] = f2bf(p6); pf[7] = f2bf(p7);
    acc = __builtin_amdgcn_mfma_f32_16x16x32_bf16(vf, pf, acc, 0, 0, 0);

    kf0 = nk0; kf1 = nk1; vf = nv; kk = kn;
  }
  PM[ks][qg][lane] = m;
  PL[ks][qg][lane] = l;
  PA[ks][qg][lane] = acc;
  __syncthreads();
  if (ks == 0) {
    float M = PM[0][qg][lane];
#pragma unroll
    for (int k = 1; k < 4; ++k) M = fmaxf(M, PM[k][qg][lane]);
    float L = 0.f;
    f32x4 o = {0.f, 0.f, 0.f, 0.f};
#pragma unroll
    for (int k = 0; k < 4; ++k) {
      float c = exp2f(PM[k][qg][lane] - M);
      L += PL[k][qg][lane] * c;
      f32x4 a = PA[k][qg][lane];
      o[0] += a[0] * c; o[1] += a[1] * c; o[2] += a[2] * c; o[3] += a[3] * c;
    }
    L += __shfl_xor(L, 16, 64);
    L += __shfl_xor(L, 32, 64);
    float inv = 1.f / L;
    int q = q0 + ql;
    int h = q / NW, wcol = q - h * NW;
    s16x4 ov;
    ov.x = f2bf(o[0] * inv);
    ov.y = f2bf(o[1] * inv);
    ov.z = f2bf(o[2] * inv);
    ov.w = f2bf(o[3] * inv);
    *(s16x4*)(aot + (((size_t)b * PH + h + 1) * PWS + wcol + 1) * 16 + g * 4) = ov;
  }
}

// ---------------- launch ----------------
extern "C" void kernel_launch(void* const* d_in, const int* in_sizes, int n_in,
                              void* d_out, int out_size, void* d_ws, size_t ws_size,
                              hipStream_t stream) {
  const float* x      = (const float*)d_in[0];
  const float* xe     = (const float*)d_in[1];
  const float* temb   = (const float*)d_in[2];
  const float* gn1w   = (const float*)d_in[3];
  const float* gn1b   = (const float*)d_in[4];
  const float* conv1w = (const float*)d_in[5];
  const float* conv1b = (const float*)d_in[6];
  const float* affw   = (const float*)d_in[7];
  const float* affb   = (const float*)d_in[8];
  const float* gn2w   = (const float*)d_in[9];
  const float* gn2b   = (const float*)d_in[10];
  const float* conv2w = (const float*)d_in[11];
  const float* conv2b = (const float*)d_in[12];
  const float* qw     = (const float*)d_in[13];
  const float* kvw    = (const float*)d_in[14];
  const float* outw   = (const float*)d_in[15];
  const float* outb   = (const float*)d_in[16];
  float* out = (float*)d_out;
  float* ws  = (float*)d_ws;

  // ws layout (f32 region first, then bf16 region)
  float* gbsum  = ws;                                    // 1,536
  float* gnpart = gbsum + NB * NC;                       // 3,072
  short* wbuf1  = (short*)(gnpart + 3072);                      // 331,776 bf16
  short* wbuf2  = wbuf1 + (size_t)6 * 9 * 12 * 64 * 8;          // 331,776 bf16
  short* wbufo  = wbuf2 + (size_t)6 * 9 * 12 * 64 * 8;          // 55,296 bf16
  short* awq    = wbufo + (size_t)9 * 12 * 64 * 8;              // 3,072 bf16
  short* awkv   = awq + 3072;                                   // 6,144 bf16
  short* actt   = awkv + 6144;                                  // 3,993,600 bf16
  short* Qb     = actt + ACT_T_ELEMS;                           // 589,824 bf16
  short* Kb     = Qb + (size_t)NB * NP * 32;                    // 589,824 bf16
  short* VTb    = Kb + (size_t)NB * NP * 32;                    // 294,912 bf16
  short* aot    = VTb + (size_t)NB * 16 * NP;                   // 332,800 bf16

  // all prep in one launch
  megaprep_kernel<<<3162, 256, 0, stream>>>(conv1w, conv2w, outw, qw, kvw, temb,
                                            affw, affb, wbuf1, wbuf2, wbufo, awq, awkv,
                                            gbsum, actt, aot);
  // kv path (independent of resnet chain) — run early
  qkv_fused_kernel<2, true><<<NB * NH, 192, 0, stream>>>(xe, awkv, Kb, VTb);

  // ----- ResnetBlock -----
  gn_stats_part_kernel<<<dim3(NB * NGROUPS, 6), 192, 0, stream>>>(x, gnpart);
  gn_apply_t_kernel<<<NB * NH, 256, 0, stream>>>(x, gnpart, gn1w, gn1b, actt);
  conv_mfma_kernel<true, false><<<dim3(NB * 24, 3), 256, 0, stream>>>(
      actt, wbuf1, conv1b, gbsum, nullptr, out);
  gn_stats_part_kernel<<<dim3(NB * NGROUPS, 6), 192, 0, stream>>>(out, gnpart);
  gn_apply_t_kernel<<<NB * NH, 256, 0, stream>>>(out, gnpart, gn2w, gn2b, actt);
  conv_mfma_kernel<false, true><<<dim3(NB * 24, 3), 256, 0, stream>>>(
      actt, wbuf2, conv2b, nullptr, x, out);

  // ----- CrossAttention -----
  qkv_fused_kernel<1, false><<<NB * NH, 192, 0, stream>>>(out, awq, Qb, nullptr);
  attn_mfma_kernel<<<dim3(36, NB), 1024, 0, stream>>>(Qb, Kb, VTb, aot);
  out_conv_mfma_kernel<<<dim3(NB * 24, 3), 256, 0, stream>>>(aot, wbufo, outb, out);
}